// Round 4
// baseline (706.832 us; speedup 1.0000x reference)
//
#include <hip/hip_runtime.h>

#define NNODES 50000
#define EDIM 64
#define WKLEN 9
#define NEDGE 800000

using bf16x8 = __attribute__((ext_vector_type(8))) __bf16;
using f32x4  = __attribute__((ext_vector_type(4))) float;

// ---- static device scratch ----
__device__ __align__(256) float g_A[NNODES * EDIM];    // 12.8 MB
__device__ __align__(256) float g_B[NNODES * EDIM];    // 12.8 MB
__device__ __align__(256) float g_mt0[NEDGE];          // 3.2 MB
__device__ __align__(256) float g_mt1[NEDGE];          // 3.2 MB
__device__ __align__(256) float g_sm0[NNODES];
__device__ __align__(256) float g_sm1[NNODES];
__device__ __align__(256) int   g_rowptr[NNODES + 1];

__device__ __forceinline__ unsigned short f2bf(float f) {
    union { float f; unsigned int i; } v;
    v.f = f;
    unsigned int r = v.i + 0x7FFFu + ((v.i >> 16) & 1u);
    return (unsigned short)(r >> 16);
}

// ---------------------------------------------------------------------------
// K0: row_ptr via binary search over sorted COO row array
// ---------------------------------------------------------------------------
__global__ __launch_bounds__(256) void rowptr_kernel(
    const int* __restrict__ row, int n, int nE)
{
    int i = blockIdx.x * 256 + threadIdx.x;
    if (i > n) return;
    int lo = 0, hi = nE;
    while (lo < hi) {
        int mid = (lo + hi) >> 1;
        if (row[mid] < i) lo = mid + 1; else hi = mid;
    }
    g_rowptr[i] = lo;
}

// ---------------------------------------------------------------------------
// K2: edge MLP (both layers) via MFMA 16x16x32 bf16 (fp32 in, bf16 staged).
// t_mask_i = sigmoid((noise + relu(cat@W1+b1)@W2 + b2) / 0.5)
// ---------------------------------------------------------------------------
__global__ __launch_bounds__(256) void edge_mlp_kernel(
    const float* __restrict__ x,       // [N,64] fp32
    const float* __restrict__ tW1,     // [2,128,64] fp32
    const float* __restrict__ tb1,     // [2,64]
    const float* __restrict__ tW2,     // [2,64]
    const float* __restrict__ tb2,     // [2]
    const float* __restrict__ tnoise,  // [2,nE]
    const int* __restrict__ row,
    const int* __restrict__ col,
    float* __restrict__ mask_out,      // fp32 out (layer 1 mask)
    int nE)
{
    __shared__ alignas(16) unsigned short sW[2][64][136]; // W1^T (bf16), padded
    __shared__ alignas(16) unsigned short sA[4][16][136]; // per-wave A tiles (bf16)
    __shared__ float sb1[2][64];
    __shared__ float sw2[2][64];

    const int tid = threadIdx.x;

    // stage W transposed + converted: sW[i][n][k] = bf16(tW1[i*8192 + k*64 + n])
    for (int idx = tid; idx < 2 * 128 * 64; idx += 256) {
        int i = idx >> 13;
        int r = idx & 8191;
        int k = r >> 6;
        int nn = r & 63;
        sW[i][nn][k] = f2bf(tW1[idx]);
    }
    if (tid < 128) {
        int i = tid >> 6, nn = tid & 63;
        sb1[i][nn] = tb1[tid];
        sw2[i][nn] = tW2[tid];
    }
    const float b2v0 = tb2[0];
    const float b2v1 = tb2[1];

    const int wave = tid >> 6;
    const int lane = tid & 63;
    const int mc = lane & 15;
    const int quad = lane >> 4;

    for (int g = 0; g < 4; ++g) {
        const int e0 = blockIdx.x * 256 + g * 64 + wave * 16;
        // stage A tile: 16 edges x 128 (row-half | col-half), fp32->bf16
#pragma unroll
        for (int t = 0; t < 4; ++t) {
            int idx = t * 64 + lane;    // 256 chunk-tasks, 8 elements each
            int el = idx >> 4;
            int c = idx & 15;
            int half = c >> 3;
            int off = (c & 7) * 8;
            int e = e0 + el;
            int node = half ? col[e] : row[e];
            const float* src = x + node * 64 + off;
            union { unsigned short s[8]; uint4 q; } u;
#pragma unroll
            for (int j = 0; j < 8; ++j) u.s[j] = f2bf(src[j]);
            *(uint4*)&sA[wave][el][half * 64 + off] = u.q;
        }
        __syncthreads();

        bf16x8 afrag[4];
#pragma unroll
        for (int ks = 0; ks < 4; ++ks)
            afrag[ks] = *(const bf16x8*)&sA[wave][mc][ks * 32 + quad * 8];

#pragma unroll
        for (int i = 0; i < 2; ++i) {
            f32x4 acc[4];
            const f32x4 zero = {0.f, 0.f, 0.f, 0.f};
#pragma unroll
            for (int nn = 0; nn < 4; ++nn) acc[nn] = zero;
#pragma unroll
            for (int ks = 0; ks < 4; ++ks) {
                bf16x8 a = afrag[ks];
#pragma unroll
                for (int nn = 0; nn < 4; ++nn) {
                    bf16x8 b = *(const bf16x8*)&sW[i][nn * 16 + mc][ks * 32 + quad * 8];
                    acc[nn] = __builtin_amdgcn_mfma_f32_16x16x32_bf16(a, b, acc[nn], 0, 0, 0);
                }
            }
            float b1v[4], w2v[4];
#pragma unroll
            for (int nn = 0; nn < 4; ++nn) {
                b1v[nn] = sb1[i][nn * 16 + mc];
                w2v[nn] = sw2[i][nn * 16 + mc];
            }
            float p[4];
#pragma unroll
            for (int r = 0; r < 4; ++r) {
                float accs = 0.f;
#pragma unroll
                for (int nn = 0; nn < 4; ++nn) {
                    float h = acc[nn][r] + b1v[nn];
                    h = fmaxf(h, 0.f);
                    accs = fmaf(h, w2v[nn], accs);
                }
                p[r] = accs;
            }
#pragma unroll
            for (int off = 8; off >= 1; off >>= 1) {
#pragma unroll
                for (int r = 0; r < 4; ++r) p[r] += __shfl_xor(p[r], off, 64);
            }
            if (mc == 0) {
                const float b2v = (i == 0) ? b2v0 : b2v1;
                const float* nz = tnoise + i * nE;
                float* mo = (i == 0) ? g_mt0 : g_mt1;
#pragma unroll
                for (int r = 0; r < 4; ++r) {
                    int e = e0 + quad * 4 + r;
                    float z = (nz[e] + p[r] + b2v) * 2.0f;
                    float mval = 1.0f / (1.0f + expf(-z));
                    mo[e] = mval;
                    if (i == 1) mask_out[e] = mval;
                }
            }
        }
        __syncthreads();
    }
}

// ---------------------------------------------------------------------------
// SpMM (fp32): wave per row, 64 lanes = 64 dims. Optional per-edge gate;
// fp32 out and/or fused epilogue outavg = (ea + eb + acc)/3.
// ---------------------------------------------------------------------------
__global__ __launch_bounds__(256) void spmm_kernel(
    const int* __restrict__ colv,
    const float* __restrict__ vals,
    const float* __restrict__ gate,    // nullable
    const float* __restrict__ h,       // [n,64]
    float* __restrict__ out32,         // nullable
    float* __restrict__ outavg,        // nullable
    const float* __restrict__ ea,
    const float* __restrict__ eb,
    int n)
{
    int w = (blockIdx.x * 256 + threadIdx.x) >> 6;
    int lane = threadIdx.x & 63;
    if (w >= n) return;
    int s = g_rowptr[w], e = g_rowptr[w + 1];
    float acc = 0.f, acc2 = 0.f;
    int j = s;
    for (; j + 1 < e; j += 2) {
        int c0 = colv[j], c1 = colv[j + 1];
        float v0 = vals[j], v1 = vals[j + 1];
        if (gate) { v0 *= gate[j]; v1 *= gate[j + 1]; }
        acc  = fmaf(v0, h[c0 * 64 + lane], acc);
        acc2 = fmaf(v1, h[c1 * 64 + lane], acc2);
    }
    if (j < e) {
        int c0 = colv[j];
        float v0 = vals[j];
        if (gate) v0 *= gate[j];
        acc = fmaf(v0, h[c0 * 64 + lane], acc);
    }
    acc += acc2;
    int o = w * 64 + lane;
    if (out32) out32[o] = acc;
    if (outavg) outavg[o] = (ea[o] + eb[o] + acc) * (1.0f / 3.0f);
}

// ---------------------------------------------------------------------------
// Random-walk mean-pool + gate: out = sm*cur + (1-sm)*meanpool(cur)
// ---------------------------------------------------------------------------
__global__ __launch_bounds__(256) void rwgate_kernel(
    const int* __restrict__ rw_col,
    const float* __restrict__ rw_vals,
    const float* __restrict__ cur,
    const float* __restrict__ smask,
    float* __restrict__ outg,
    int n)
{
    int w = (blockIdx.x * 256 + threadIdx.x) >> 6;
    int lane = threadIdx.x & 63;
    if (w >= n) return;
    float mp = 0.f;
    int base = w * WKLEN;
#pragma unroll
    for (int j = 0; j < WKLEN; ++j) {
        int c = rw_col[base + j];
        mp = fmaf(rw_vals[base + j], cur[c * 64 + lane], mp);
    }
    float sm = smask[w];
    outg[w * 64 + lane] = sm * cur[w * 64 + lane] + (1.f - sm) * mp;
}

// ---------------------------------------------------------------------------
// Node MLP (s-mask): wave per node, shuffle-broadcast over K=64. fp32.
// ---------------------------------------------------------------------------
__global__ __launch_bounds__(256) void node_mlp_kernel(
    const float* __restrict__ cur,
    const float* __restrict__ W1,    // [64*64] (layer slice)
    const float* __restrict__ b1,    // [64]
    const float* __restrict__ W2,    // [64]
    const float* __restrict__ b2,    // [1]
    const float* __restrict__ noise, // [n]
    float* __restrict__ smask,
    int n)
{
    __shared__ float sW[64][65];
    __shared__ float sb[64], sw2[64];
    int tid = threadIdx.x;
    for (int idx = tid; idx < 4096; idx += 256)
        sW[idx >> 6][idx & 63] = W1[idx];
    if (tid < 64) { sb[tid] = b1[tid]; sw2[tid] = W2[tid]; }
    __syncthreads();
    int w = (blockIdx.x * 256 + tid) >> 6;
    int lane = tid & 63;
    if (w >= n) return;
    float xv = cur[w * 64 + lane];
    float h = sb[lane];
#pragma unroll
    for (int k = 0; k < 64; ++k) {
        float ck = __shfl(xv, k, 64);
        h = fmaf(ck, sW[k][lane], h);
    }
    h = fmaxf(h, 0.f);
    float p = h * sw2[lane];
#pragma unroll
    for (int off = 32; off >= 1; off >>= 1) p += __shfl_xor(p, off, 64);
    if (lane == 0) {
        float z = (noise[w] + p + b2[0]) * 2.0f;
        smask[w] = 1.0f / (1.0f + expf(-z));
    }
}

// ---------------------------------------------------------------------------
// Final scalars: t_reg = 0, s_reg = (sum(sm0)+sum(sm1)) / (2n)
// ---------------------------------------------------------------------------
__global__ __launch_bounds__(256) void finalize_kernel(
    float* __restrict__ out, int n)
{
    __shared__ float red[256];
    float s = 0.f;
    for (int i = threadIdx.x; i < n; i += 256) s += g_sm0[i] + g_sm1[i];
    red[threadIdx.x] = s;
    __syncthreads();
    for (int off = 128; off >= 1; off >>= 1) {
        if (threadIdx.x < off) red[threadIdx.x] += red[threadIdx.x + off];
        __syncthreads();
    }
    if (threadIdx.x == 0) {
        out[6400000] = 0.0f;               // t_reg
        out[6400001] = red[0] / (2.0f * n); // s_reg
    }
}

extern "C" void kernel_launch(void* const* d_in, const int* in_sizes, int n_in,
                              void* d_out, int out_size, void* d_ws, size_t ws_size,
                              hipStream_t stream)
{
    const float* x    = (const float*)d_in[0];
    const float* vals = (const float*)d_in[1];
    const float* rwv  = (const float*)d_in[2];
    const float* tW1  = (const float*)d_in[3];
    const float* tb1  = (const float*)d_in[4];
    const float* tW2  = (const float*)d_in[5];
    const float* tb2  = (const float*)d_in[6];
    const float* sW1  = (const float*)d_in[7];
    const float* sb1  = (const float*)d_in[8];
    const float* sW2  = (const float*)d_in[9];
    const float* sb2  = (const float*)d_in[10];
    const float* tnz  = (const float*)d_in[11];
    const float* snz  = (const float*)d_in[12];
    const int* row   = (const int*)d_in[13];
    const int* colv  = (const int*)d_in[14];
    const int* rwcol = (const int*)d_in[16];

    const int n = NNODES;
    const int nE = in_sizes[1];   // 800000

    float* out   = (float*)d_out;
    float* emb_t = out;
    float* emb_s = out + 3200000;
    float* masko = out + 6400002;

    float *A, *B, *mt0, *mt1, *sm0p, *sm1p;
    hipGetSymbolAddress((void**)&A, HIP_SYMBOL(g_A));
    hipGetSymbolAddress((void**)&B, HIP_SYMBOL(g_B));
    hipGetSymbolAddress((void**)&mt0, HIP_SYMBOL(g_mt0));
    hipGetSymbolAddress((void**)&mt1, HIP_SYMBOL(g_mt1));
    hipGetSymbolAddress((void**)&sm0p, HIP_SYMBOL(g_sm0));
    hipGetSymbolAddress((void**)&sm1p, HIP_SYMBOL(g_sm1));

    // K0: row_ptr
    rowptr_kernel<<<(n + 256) / 256, 256, 0, stream>>>(row, n, nE);
    // K2: edge MLP -> g_mt0, g_mt1, mask output
    edge_mlp_kernel<<<nE / 256, 256, 0, stream>>>(x, tW1, tb1, tW2, tb2, tnz,
                                                  row, colv, masko, nE);
    // K3: A = cur1 = spmm(vals, x)
    spmm_kernel<<<(n * 64) / 256, 256, 0, stream>>>(colv, vals, nullptr, x,
                                                    A, nullptr, nullptr, nullptr, n);
    // K4: sm0 from cur1
    node_mlp_kernel<<<(n * 64) / 256, 256, 0, stream>>>(A, sW1, sb1, sW2, sb2, snz, sm0p, n);
    // K5: B = cur2 = spmm(vals, cur1)
    spmm_kernel<<<(n * 64) / 256, 256, 0, stream>>>(colv, vals, nullptr, A,
                                                    B, nullptr, nullptr, nullptr, n);
    // K6: sm1 from cur2 (layer-1 slices)
    node_mlp_kernel<<<(n * 64) / 256, 256, 0, stream>>>(B, sW1 + 4096, sb1 + 64,
                                                        sW2 + 64, sb2 + 1, snz + n, sm1p, n);
    // K7: A = t1 = spmm(vals*mt0, x)
    spmm_kernel<<<(n * 64) / 256, 256, 0, stream>>>(colv, vals, mt0, x,
                                                    A, nullptr, nullptr, nullptr, n);
    // K8: emb_t = (x + t1 + spmm(vals*mt1, t1)) / 3
    spmm_kernel<<<(n * 64) / 256, 256, 0, stream>>>(colv, vals, mt1, A,
                                                    nullptr, emb_t, x, A, n);
    // K9: B = g0 = sm0*x + (1-sm0)*rwpool(x)
    rwgate_kernel<<<(n * 64) / 256, 256, 0, stream>>>(rwcol, rwv, x, sm0p, B, n);
    // K10: A = c1 = spmm(vals, g0)
    spmm_kernel<<<(n * 64) / 256, 256, 0, stream>>>(colv, vals, nullptr, B,
                                                    A, nullptr, nullptr, nullptr, n);
    // K11: B = g1 = sm1*c1 + (1-sm1)*rwpool(c1)
    rwgate_kernel<<<(n * 64) / 256, 256, 0, stream>>>(rwcol, rwv, A, sm1p, B, n);
    // K12: emb_s = (x + c1 + spmm(vals, g1)) / 3
    spmm_kernel<<<(n * 64) / 256, 256, 0, stream>>>(colv, vals, nullptr, B,
                                                    nullptr, emb_s, x, A, n);
    // K13: scalars
    finalize_kernel<<<1, 256, 0, stream>>>(out, n);
}

// Round 5
// 571.571 us; speedup vs baseline: 1.2366x; 1.2366x over previous
//
#include <hip/hip_runtime.h>

#define NNODES 50000
#define EDIM 64
#define WKLEN 9
#define NEDGE 800000

using bf16x8 = __attribute__((ext_vector_type(8))) __bf16;
using f32x4  = __attribute__((ext_vector_type(4))) float;

// ---- static device scratch ----
__device__ __align__(256) float g_A[NNODES * EDIM];       // 12.8 MB (g0 / g1)
__device__ __align__(256) float g_B[NNODES * EDIM];       // 12.8 MB (c1)
__device__ __align__(256) float g_AB[NNODES * 128];       // 25.6 MB (cur1|t1 interleaved)
__device__ __align__(256) float g_mt0[NEDGE];             // 3.2 MB
__device__ __align__(256) float g_mt1[NEDGE];             // 3.2 MB
__device__ __align__(256) float g_sm0[NNODES];
__device__ __align__(256) float g_sm1[NNODES];
__device__ __align__(256) int   g_rowptr[NNODES + 1];
__device__ __align__(256) unsigned short g_xbf[NNODES * EDIM];  // 6.4 MB bf16 x
__device__ __align__(256) unsigned short g_Bswz[2048 * 8];      // 32 KB swizzled W1 frags

__device__ __forceinline__ unsigned short f2bf(float f) {
    union { float f; unsigned int i; } v;
    v.f = f;
    unsigned int r = v.i + 0x7FFFu + ((v.i >> 16) & 1u);
    return (unsigned short)(r >> 16);
}

// ---------------------------------------------------------------------------
// K0: row_ptr via binary search over sorted COO row array
// ---------------------------------------------------------------------------
__global__ __launch_bounds__(256) void rowptr_kernel(
    const int* __restrict__ row, int n, int nE)
{
    int i = blockIdx.x * 256 + threadIdx.x;
    if (i > n) return;
    int lo = 0, hi = nE;
    while (lo < hi) {
        int mid = (lo + hi) >> 1;
        if (row[mid] < i) lo = mid + 1; else hi = mid;
    }
    g_rowptr[i] = lo;
}

// ---------------------------------------------------------------------------
// K1: prep — x -> bf16, W1 -> lane-swizzled bf16 fragments
// frag f = i*16+ks*4+nn; lane (mc,quad); elem j: W1[i][ks*32+quad*8+j][nn*16+mc]
// ---------------------------------------------------------------------------
__global__ __launch_bounds__(256) void prep_kernel(
    const float* __restrict__ x, const float* __restrict__ tW1, int n8)
{
    int i = blockIdx.x * 256 + threadIdx.x;
    if (i < n8) {
        const float* src = x + i * 8;
        union { unsigned short s[8]; uint4 q; } u;
#pragma unroll
        for (int j = 0; j < 8; ++j) u.s[j] = f2bf(src[j]);
        *(uint4*)&g_xbf[i * 8] = u.q;
    }
    if (blockIdx.x < 8) {
        int t = blockIdx.x * 256 + threadIdx.x;   // 0..2047
        int li = t >> 10, ks = (t >> 8) & 3, nn = (t >> 6) & 3, ln = t & 63;
        int q = ln >> 4, mcl = ln & 15;
        union { unsigned short s[8]; uint4 q4; } u;
#pragma unroll
        for (int j = 0; j < 8; ++j)
            u.s[j] = f2bf(tW1[li * 8192 + (ks * 32 + q * 8 + j) * 64 + nn * 16 + mcl]);
        *(uint4*)&g_Bswz[t * 8] = u.q4;
    }
}

// ---------------------------------------------------------------------------
// K2: edge MLP via MFMA — A gathered direct-from-global (bf16 x),
// B register-resident, no LDS.
// ---------------------------------------------------------------------------
__global__ __launch_bounds__(256, 2) void edge_mlp_kernel(
    const float* __restrict__ tb1,     // [2,64]
    const float* __restrict__ tW2,     // [2,64]
    const float* __restrict__ tb2,     // [2]
    const float* __restrict__ tnoise,  // [2,nE]
    const int* __restrict__ row,
    const int* __restrict__ col,
    float* __restrict__ mask_out,      // fp32 out (layer-1 mask)
    int nE)
{
    const int tid = threadIdx.x;
    const int wave = tid >> 6, lane = tid & 63;
    const int mc = lane & 15, quad = lane >> 4;

    // B fragments: 32 x bf16x8 = 128 VGPRs, same for all waves
    bf16x8 B[2][4][4];
#pragma unroll
    for (int f = 0; f < 32; ++f) {
        int i = f >> 4, ks = (f >> 2) & 3, nn = f & 3;
        B[i][ks][nn] = *(const bf16x8*)&g_Bswz[(f * 64 + lane) * 8];
    }
    float b1v[2][4], w2v[2][4];
#pragma unroll
    for (int i = 0; i < 2; ++i)
#pragma unroll
        for (int nn = 0; nn < 4; ++nn) {
            b1v[i][nn] = tb1[i * 64 + nn * 16 + mc];
            w2v[i][nn] = tW2[i * 64 + nn * 16 + mc];
        }
    const float b2v[2] = { tb2[0], tb2[1] };
    const int base = blockIdx.x * 256;

    auto loadA = [&](int g, bf16x8* af) {
        int e = base + g * 64 + wave * 16 + mc;
        int rn = row[e], cn = col[e];
        const unsigned short* pr = g_xbf + rn * 64 + quad * 8;
        const unsigned short* pc = g_xbf + cn * 64 + quad * 8;
        af[0] = *(const bf16x8*)pr;
        af[1] = *(const bf16x8*)(pr + 32);
        af[2] = *(const bf16x8*)pc;
        af[3] = *(const bf16x8*)(pc + 32);
    };

    bf16x8 afC[4], afN[4];
    loadA(0, afC);
    for (int g = 0; g < 4; ++g) {
        if (g < 3) loadA(g + 1, afN);
#pragma unroll
        for (int i = 0; i < 2; ++i) {
            f32x4 acc[4];
            const f32x4 zero = {0.f, 0.f, 0.f, 0.f};
#pragma unroll
            for (int nn = 0; nn < 4; ++nn) acc[nn] = zero;
#pragma unroll
            for (int ks = 0; ks < 4; ++ks)
#pragma unroll
                for (int nn = 0; nn < 4; ++nn)
                    acc[nn] = __builtin_amdgcn_mfma_f32_16x16x32_bf16(
                        afC[ks], B[i][ks][nn], acc[nn], 0, 0, 0);
            float p[4];
#pragma unroll
            for (int r = 0; r < 4; ++r) {
                float s = 0.f;
#pragma unroll
                for (int nn = 0; nn < 4; ++nn) {
                    float h = acc[nn][r] + b1v[i][nn];
                    s = fmaf(fmaxf(h, 0.f), w2v[i][nn], s);
                }
                p[r] = s;
            }
#pragma unroll
            for (int off = 8; off >= 1; off >>= 1)
#pragma unroll
                for (int r = 0; r < 4; ++r) p[r] += __shfl_xor(p[r], off, 64);
            if (mc == 0) {
                const float* nz = tnoise + i * nE;
                float* mo = (i == 0) ? g_mt0 : g_mt1;
#pragma unroll
                for (int r = 0; r < 4; ++r) {
                    int e = base + g * 64 + wave * 16 + quad * 4 + r;
                    float z = (nz[e] + p[r] + b2v[i]) * 2.0f;
                    float mval = 1.0f / (1.0f + expf(-z));
                    mo[e] = mval;
                    if (i == 1) mask_out[e] = mval;
                }
            }
        }
#pragma unroll
        for (int ks = 0; ks < 4; ++ks) afC[ks] = afN[ks];
    }
}

// ---------------------------------------------------------------------------
// S1: fused cur1=spmm(vals,x) + t1=spmm(vals*mt0,x)  [one gather, two accs]
//     + node-MLP epilogue -> sm0. Writes g_AB interleaved [w][cur1|t1].
// ---------------------------------------------------------------------------
__global__ __launch_bounds__(256) void s1_kernel(
    const int* __restrict__ colv,
    const float* __restrict__ vals,
    const float* __restrict__ x,
    const float* __restrict__ W1,    // layer0 [64*64]
    const float* __restrict__ b1,
    const float* __restrict__ W2,
    const float* __restrict__ b2,
    const float* __restrict__ noise, // [n]
    int n)
{
    __shared__ float sW[64][65];
    __shared__ float sb[64], sw2[64];
    int tid = threadIdx.x;
    for (int idx = tid; idx < 4096; idx += 256)
        sW[idx >> 6][idx & 63] = W1[idx];
    if (tid < 64) { sb[tid] = b1[tid]; sw2[tid] = W2[tid]; }
    __syncthreads();

    int w = (blockIdx.x * 256 + tid) >> 6;
    int lane = tid & 63;
    int s = g_rowptr[w], e = g_rowptr[w + 1];
    float ap = 0.f, ag = 0.f, ap2 = 0.f, ag2 = 0.f;
    int j = s;
    for (; j + 1 < e; j += 2) {
        int c0 = colv[j], c1 = colv[j + 1];
        float v0 = vals[j], v1 = vals[j + 1];
        float m0 = g_mt0[j], m1 = g_mt0[j + 1];
        float x0 = x[c0 * 64 + lane], x1 = x[c1 * 64 + lane];
        ap  = fmaf(v0, x0, ap);   ag  = fmaf(v0 * m0, x0, ag);
        ap2 = fmaf(v1, x1, ap2);  ag2 = fmaf(v1 * m1, x1, ag2);
    }
    if (j < e) {
        int c0 = colv[j];
        float v0 = vals[j], m0 = g_mt0[j];
        float x0 = x[c0 * 64 + lane];
        ap = fmaf(v0, x0, ap); ag = fmaf(v0 * m0, x0, ag);
    }
    ap += ap2; ag += ag2;
    g_AB[w * 128 + lane]      = ap;   // cur1
    g_AB[w * 128 + 64 + lane] = ag;   // t1

    // sm0 epilogue
    float h = sb[lane];
#pragma unroll
    for (int k = 0; k < 64; ++k)
        h = fmaf(__shfl(ap, k, 64), sW[k][lane], h);
    h = fmaxf(h, 0.f);
    float p = h * sw2[lane];
#pragma unroll
    for (int off = 32; off >= 1; off >>= 1) p += __shfl_xor(p, off, 64);
    if (lane == 0) {
        float z = (noise[w] + p + b2[0]) * 2.0f;
        g_sm0[w] = 1.0f / (1.0f + expf(-z));
    }
}

// ---------------------------------------------------------------------------
// S2: fused cur2=spmm(vals,cur1) + t2=spmm(vals*mt1,t1) (interleaved gathers)
//     + emb_t=(x+t1+t2)/3 + node-MLP epilogue -> sm1 (cur2 never stored).
// ---------------------------------------------------------------------------
__global__ __launch_bounds__(256) void s2_kernel(
    const int* __restrict__ colv,
    const float* __restrict__ vals,
    const float* __restrict__ x,
    const float* __restrict__ W1,    // layer1 [64*64]
    const float* __restrict__ b1,
    const float* __restrict__ W2,
    const float* __restrict__ b2,
    const float* __restrict__ noise, // layer1 [n]
    float* __restrict__ emb_t,
    int n)
{
    __shared__ float sW[64][65];
    __shared__ float sb[64], sw2[64];
    int tid = threadIdx.x;
    for (int idx = tid; idx < 4096; idx += 256)
        sW[idx >> 6][idx & 63] = W1[idx];
    if (tid < 64) { sb[tid] = b1[tid]; sw2[tid] = W2[tid]; }
    __syncthreads();

    int w = (blockIdx.x * 256 + tid) >> 6;
    int lane = tid & 63;
    int s = g_rowptr[w], e = g_rowptr[w + 1];
    float ac = 0.f, at = 0.f, ac2 = 0.f, at2 = 0.f;
    int j = s;
    for (; j + 1 < e; j += 2) {
        int c0 = colv[j], c1 = colv[j + 1];
        float v0 = vals[j], v1 = vals[j + 1];
        float m0 = g_mt1[j], m1 = g_mt1[j + 1];
        ac  = fmaf(v0, g_AB[c0 * 128 + lane], ac);
        at  = fmaf(v0 * m0, g_AB[c0 * 128 + 64 + lane], at);
        ac2 = fmaf(v1, g_AB[c1 * 128 + lane], ac2);
        at2 = fmaf(v1 * m1, g_AB[c1 * 128 + 64 + lane], at2);
    }
    if (j < e) {
        int c0 = colv[j];
        float v0 = vals[j], m0 = g_mt1[j];
        ac = fmaf(v0, g_AB[c0 * 128 + lane], ac);
        at = fmaf(v0 * m0, g_AB[c0 * 128 + 64 + lane], at);
    }
    ac += ac2; at += at2;
    int o = w * 64 + lane;
    emb_t[o] = (x[o] + g_AB[w * 128 + 64 + lane] + at) * (1.0f / 3.0f);

    // sm1 epilogue from cur2 = ac
    float h = sb[lane];
#pragma unroll
    for (int k = 0; k < 64; ++k)
        h = fmaf(__shfl(ac, k, 64), sW[k][lane], h);
    h = fmaxf(h, 0.f);
    float p = h * sw2[lane];
#pragma unroll
    for (int off = 32; off >= 1; off >>= 1) p += __shfl_xor(p, off, 64);
    if (lane == 0) {
        float z = (noise[w] + p + b2[0]) * 2.0f;
        g_sm1[w] = 1.0f / (1.0f + expf(-z));
    }
}

// ---------------------------------------------------------------------------
// Generic SpMM (fp32), optional fused epilogue outavg = (ea+eb+acc)/3.
// ---------------------------------------------------------------------------
__global__ __launch_bounds__(256) void spmm_kernel(
    const int* __restrict__ colv,
    const float* __restrict__ vals,
    const float* __restrict__ h,
    float* __restrict__ out32,         // nullable
    float* __restrict__ outavg,        // nullable
    const float* __restrict__ ea,
    const float* __restrict__ eb,
    int n)
{
    int w = (blockIdx.x * 256 + threadIdx.x) >> 6;
    int lane = threadIdx.x & 63;
    if (w >= n) return;
    int s = g_rowptr[w], e = g_rowptr[w + 1];
    float acc = 0.f, acc2 = 0.f;
    int j = s;
    for (; j + 1 < e; j += 2) {
        int c0 = colv[j], c1 = colv[j + 1];
        acc  = fmaf(vals[j],     h[c0 * 64 + lane], acc);
        acc2 = fmaf(vals[j + 1], h[c1 * 64 + lane], acc2);
    }
    if (j < e) acc = fmaf(vals[j], h[colv[j] * 64 + lane], acc);
    acc += acc2;
    int o = w * 64 + lane;
    if (out32) out32[o] = acc;
    if (outavg) outavg[o] = (ea[o] + eb[o] + acc) * (1.0f / 3.0f);
}

// ---------------------------------------------------------------------------
// Random-walk mean-pool + gate: out = sm*cur + (1-sm)*meanpool(cur)
// ---------------------------------------------------------------------------
__global__ __launch_bounds__(256) void rwgate_kernel(
    const int* __restrict__ rw_col,
    const float* __restrict__ rw_vals,
    const float* __restrict__ cur,
    const float* __restrict__ smask,
    float* __restrict__ outg,
    int n)
{
    int w = (blockIdx.x * 256 + threadIdx.x) >> 6;
    int lane = threadIdx.x & 63;
    if (w >= n) return;
    float mp = 0.f;
    int base = w * WKLEN;
#pragma unroll
    for (int j = 0; j < WKLEN; ++j) {
        int c = rw_col[base + j];
        mp = fmaf(rw_vals[base + j], cur[c * 64 + lane], mp);
    }
    float sm = smask[w];
    outg[w * 64 + lane] = sm * cur[w * 64 + lane] + (1.f - sm) * mp;
}

// ---------------------------------------------------------------------------
// Final scalars
// ---------------------------------------------------------------------------
__global__ __launch_bounds__(256) void finalize_kernel(
    float* __restrict__ out, int n)
{
    __shared__ float red[256];
    float s = 0.f;
    for (int i = threadIdx.x; i < n; i += 256) s += g_sm0[i] + g_sm1[i];
    red[threadIdx.x] = s;
    __syncthreads();
    for (int off = 128; off >= 1; off >>= 1) {
        if (threadIdx.x < off) red[threadIdx.x] += red[threadIdx.x + off];
        __syncthreads();
    }
    if (threadIdx.x == 0) {
        out[6400000] = 0.0f;                // t_reg
        out[6400001] = red[0] / (2.0f * n); // s_reg
    }
}

extern "C" void kernel_launch(void* const* d_in, const int* in_sizes, int n_in,
                              void* d_out, int out_size, void* d_ws, size_t ws_size,
                              hipStream_t stream)
{
    const float* x    = (const float*)d_in[0];
    const float* vals = (const float*)d_in[1];
    const float* rwv  = (const float*)d_in[2];
    const float* tW1  = (const float*)d_in[3];
    const float* tb1  = (const float*)d_in[4];
    const float* tW2  = (const float*)d_in[5];
    const float* tb2  = (const float*)d_in[6];
    const float* sW1  = (const float*)d_in[7];
    const float* sb1  = (const float*)d_in[8];
    const float* sW2  = (const float*)d_in[9];
    const float* sb2  = (const float*)d_in[10];
    const float* tnz  = (const float*)d_in[11];
    const float* snz  = (const float*)d_in[12];
    const int* row   = (const int*)d_in[13];
    const int* colv  = (const int*)d_in[14];
    const int* rwcol = (const int*)d_in[16];

    const int n = NNODES;
    const int nE = in_sizes[1];   // 800000

    float* out   = (float*)d_out;
    float* emb_t = out;
    float* emb_s = out + 3200000;
    float* masko = out + 6400002;

    float *A, *B;
    hipGetSymbolAddress((void**)&A, HIP_SYMBOL(g_A));
    hipGetSymbolAddress((void**)&B, HIP_SYMBOL(g_B));
    float *sm0p, *sm1p;
    hipGetSymbolAddress((void**)&sm0p, HIP_SYMBOL(g_sm0));
    hipGetSymbolAddress((void**)&sm1p, HIP_SYMBOL(g_sm1));

    // K0: row_ptr
    rowptr_kernel<<<(n + 256) / 256, 256, 0, stream>>>(row, n, nE);
    // K1: prep (x->bf16, W1 swizzle)
    prep_kernel<<<1563, 256, 0, stream>>>(x, tW1, n * EDIM / 8);
    // K2: edge MLP -> g_mt0, g_mt1, mask output
    edge_mlp_kernel<<<nE / 256, 256, 0, stream>>>(tb1, tW2, tb2, tnz,
                                                  row, colv, masko, nE);
    // S1: cur1,t1 (one gather pass) + sm0
    s1_kernel<<<(n * 64) / 256, 256, 0, stream>>>(colv, vals, x,
                                                  sW1, sb1, sW2, sb2, snz, n);
    // S2: emb_t + sm1 (cur2 in-register)
    s2_kernel<<<(n * 64) / 256, 256, 0, stream>>>(colv, vals, x,
                                                  sW1 + 4096, sb1 + 64, sW2 + 64,
                                                  sb2 + 1, snz + n, emb_t, n);
    // K9: A = g0 = sm0*x + (1-sm0)*rwpool(x)
    rwgate_kernel<<<(n * 64) / 256, 256, 0, stream>>>(rwcol, rwv, x, sm0p, A, n);
    // K10: B = c1 = spmm(vals, g0)
    spmm_kernel<<<(n * 64) / 256, 256, 0, stream>>>(colv, vals, A,
                                                    B, nullptr, nullptr, nullptr, n);
    // K11: A = g1 = sm1*c1 + (1-sm1)*rwpool(c1)
    rwgate_kernel<<<(n * 64) / 256, 256, 0, stream>>>(rwcol, rwv, B, sm1p, A, n);
    // K12: emb_s = (x + c1 + spmm(vals, g1)) / 3
    spmm_kernel<<<(n * 64) / 256, 256, 0, stream>>>(colv, vals, A,
                                                    nullptr, emb_s, x, B, n);
    // K13: scalars
    finalize_kernel<<<1, 256, 0, stream>>>(out, n);
}

// Round 6
// 509.380 us; speedup vs baseline: 1.3876x; 1.1221x over previous
//
#include <hip/hip_runtime.h>

#define NNODES 50000
#define EDIM 64
#define WKLEN 9
#define NEDGE 800000

using bf16x8 = __attribute__((ext_vector_type(8))) __bf16;
using f32x4  = __attribute__((ext_vector_type(4))) float;

// ---- static device scratch ----
__device__ __align__(256) unsigned short g_xbf[NNODES * EDIM];   // 6.4 MB bf16 x
__device__ __align__(256) unsigned short g_ABh[NNODES * 128];    // 12.8 MB packed (cur1,t1) bf16x2
__device__ __align__(256) unsigned short g_Ah[NNODES * EDIM];    // 6.4 MB (g0 / g1)
__device__ __align__(256) unsigned short g_Bh[NNODES * EDIM];    // 6.4 MB (c1)
__device__ __align__(256) float g_mt0[NEDGE];                    // 3.2 MB
__device__ __align__(256) float g_mt1[NEDGE];                    // 3.2 MB
__device__ __align__(256) float g_sm0[NNODES];
__device__ __align__(256) float g_sm1[NNODES];
__device__ __align__(256) int   g_rowptr[NNODES + 1];
__device__ __align__(256) unsigned short g_Bswz[2048 * 8];       // 32 KB swizzled W1 frags

__device__ __forceinline__ unsigned short f2bf(float f) {
    union { float f; unsigned int i; } v;
    v.f = f;
    unsigned int r = v.i + 0x7FFFu + ((v.i >> 16) & 1u);
    return (unsigned short)(r >> 16);
}
__device__ __forceinline__ float bf2f(unsigned short u) {
    union { unsigned int i; float f; } v;
    v.i = ((unsigned int)u) << 16;
    return v.f;
}
__device__ __forceinline__ float bf2f_lo(unsigned int u) {
    union { unsigned int i; float f; } v;
    v.i = u << 16;
    return v.f;
}
__device__ __forceinline__ float bf2f_hi(unsigned int u) {
    union { unsigned int i; float f; } v;
    v.i = u & 0xFFFF0000u;
    return v.f;
}

// ---------------------------------------------------------------------------
// K0: row_ptr via binary search over sorted COO row array
// ---------------------------------------------------------------------------
__global__ __launch_bounds__(256) void rowptr_kernel(
    const int* __restrict__ row, int n, int nE)
{
    int i = blockIdx.x * 256 + threadIdx.x;
    if (i > n) return;
    int lo = 0, hi = nE;
    while (lo < hi) {
        int mid = (lo + hi) >> 1;
        if (row[mid] < i) lo = mid + 1; else hi = mid;
    }
    g_rowptr[i] = lo;
}

// ---------------------------------------------------------------------------
// K1: prep — x -> bf16, W1 -> lane-swizzled bf16 fragments
// ---------------------------------------------------------------------------
__global__ __launch_bounds__(256) void prep_kernel(
    const float* __restrict__ x, const float* __restrict__ tW1, int n8)
{
    int i = blockIdx.x * 256 + threadIdx.x;
    if (i < n8) {
        const float* src = x + i * 8;
        union { unsigned short s[8]; uint4 q; } u;
#pragma unroll
        for (int j = 0; j < 8; ++j) u.s[j] = f2bf(src[j]);
        *(uint4*)&g_xbf[i * 8] = u.q;
    }
    if (blockIdx.x < 8) {
        int t = blockIdx.x * 256 + threadIdx.x;   // 0..2047
        int li = t >> 10, ks = (t >> 8) & 3, nn = (t >> 6) & 3, ln = t & 63;
        int q = ln >> 4, mcl = ln & 15;
        union { unsigned short s[8]; uint4 q4; } u;
#pragma unroll
        for (int j = 0; j < 8; ++j)
            u.s[j] = f2bf(tW1[li * 8192 + (ks * 32 + q * 8 + j) * 64 + nn * 16 + mcl]);
        *(uint4*)&g_Bswz[t * 8] = u.q4;
    }
}

// ---------------------------------------------------------------------------
// K2: edge MLP via MFMA — A gathered direct-from-global (bf16 x),
// B register-resident, no LDS.
// ---------------------------------------------------------------------------
__global__ __launch_bounds__(256, 2) void edge_mlp_kernel(
    const float* __restrict__ tb1,
    const float* __restrict__ tW2,
    const float* __restrict__ tb2,
    const float* __restrict__ tnoise,
    const int* __restrict__ row,
    const int* __restrict__ col,
    float* __restrict__ mask_out,
    int nE)
{
    const int tid = threadIdx.x;
    const int wave = tid >> 6, lane = tid & 63;
    const int mc = lane & 15, quad = lane >> 4;

    bf16x8 B[2][4][4];
#pragma unroll
    for (int f = 0; f < 32; ++f) {
        int i = f >> 4, ks = (f >> 2) & 3, nn = f & 3;
        B[i][ks][nn] = *(const bf16x8*)&g_Bswz[(f * 64 + lane) * 8];
    }
    float b1v[2][4], w2v[2][4];
#pragma unroll
    for (int i = 0; i < 2; ++i)
#pragma unroll
        for (int nn = 0; nn < 4; ++nn) {
            b1v[i][nn] = tb1[i * 64 + nn * 16 + mc];
            w2v[i][nn] = tW2[i * 64 + nn * 16 + mc];
        }
    const float b2v[2] = { tb2[0], tb2[1] };
    const int base = blockIdx.x * 256;

    auto loadA = [&](int g, bf16x8* af) {
        int e = base + g * 64 + wave * 16 + mc;
        int rn = row[e], cn = col[e];
        const unsigned short* pr = g_xbf + rn * 64 + quad * 8;
        const unsigned short* pc = g_xbf + cn * 64 + quad * 8;
        af[0] = *(const bf16x8*)pr;
        af[1] = *(const bf16x8*)(pr + 32);
        af[2] = *(const bf16x8*)pc;
        af[3] = *(const bf16x8*)(pc + 32);
    };

    bf16x8 afC[4], afN[4];
    loadA(0, afC);
    for (int g = 0; g < 4; ++g) {
        if (g < 3) loadA(g + 1, afN);
#pragma unroll
        for (int i = 0; i < 2; ++i) {
            f32x4 acc[4];
            const f32x4 zero = {0.f, 0.f, 0.f, 0.f};
#pragma unroll
            for (int nn = 0; nn < 4; ++nn) acc[nn] = zero;
#pragma unroll
            for (int ks = 0; ks < 4; ++ks)
#pragma unroll
                for (int nn = 0; nn < 4; ++nn)
                    acc[nn] = __builtin_amdgcn_mfma_f32_16x16x32_bf16(
                        afC[ks], B[i][ks][nn], acc[nn], 0, 0, 0);
            float p[4];
#pragma unroll
            for (int r = 0; r < 4; ++r) {
                float s = 0.f;
#pragma unroll
                for (int nn = 0; nn < 4; ++nn) {
                    float h = acc[nn][r] + b1v[i][nn];
                    s = fmaf(fmaxf(h, 0.f), w2v[i][nn], s);
                }
                p[r] = s;
            }
#pragma unroll
            for (int off = 8; off >= 1; off >>= 1)
#pragma unroll
                for (int r = 0; r < 4; ++r) p[r] += __shfl_xor(p[r], off, 64);
            if (mc == 0) {
                const float* nz = tnoise + i * nE;
                float* mo = (i == 0) ? g_mt0 : g_mt1;
#pragma unroll
                for (int r = 0; r < 4; ++r) {
                    int e = base + g * 64 + wave * 16 + quad * 4 + r;
                    float z = (nz[e] + p[r] + b2v[i]) * 2.0f;
                    float mval = 1.0f / (1.0f + expf(-z));
                    mo[e] = mval;
                    if (i == 1) mask_out[e] = mval;
                }
            }
        }
#pragma unroll
        for (int ks = 0; ks < 4; ++ks) afC[ks] = afN[ks];
    }
}

// ---------------------------------------------------------------------------
// S1: fused cur1=spmm(vals,x)+t1=spmm(vals*mt0,x), bf16 gather, packed write,
//     + node-MLP epilogue -> sm0.
// ---------------------------------------------------------------------------
__global__ __launch_bounds__(256) void s1_kernel(
    const int* __restrict__ colv,
    const float* __restrict__ vals,
    const float* __restrict__ W1,
    const float* __restrict__ b1,
    const float* __restrict__ W2,
    const float* __restrict__ b2,
    const float* __restrict__ noise,
    int n)
{
    __shared__ float sW[64][65];
    __shared__ float sb[64], sw2[64];
    int tid = threadIdx.x;
    for (int idx = tid; idx < 4096; idx += 256)
        sW[idx >> 6][idx & 63] = W1[idx];
    if (tid < 64) { sb[tid] = b1[tid]; sw2[tid] = W2[tid]; }
    __syncthreads();

    int w = (blockIdx.x * 256 + tid) >> 6;
    int lane = tid & 63;
    int s = g_rowptr[w], e = g_rowptr[w + 1];
    float ap0 = 0.f, ap1 = 0.f, ap2 = 0.f, ap3 = 0.f;
    float ag0 = 0.f, ag1 = 0.f, ag2 = 0.f, ag3 = 0.f;
    int j = s;
    for (; j + 3 < e; j += 4) {
        int c0 = colv[j], c1 = colv[j + 1], c2 = colv[j + 2], c3 = colv[j + 3];
        float x0 = bf2f(g_xbf[c0 * 64 + lane]);
        float x1 = bf2f(g_xbf[c1 * 64 + lane]);
        float x2 = bf2f(g_xbf[c2 * 64 + lane]);
        float x3 = bf2f(g_xbf[c3 * 64 + lane]);
        float v0 = vals[j], v1 = vals[j + 1], v2 = vals[j + 2], v3 = vals[j + 3];
        float m0 = g_mt0[j], m1 = g_mt0[j + 1], m2 = g_mt0[j + 2], m3 = g_mt0[j + 3];
        ap0 = fmaf(v0, x0, ap0); ag0 = fmaf(v0 * m0, x0, ag0);
        ap1 = fmaf(v1, x1, ap1); ag1 = fmaf(v1 * m1, x1, ag1);
        ap2 = fmaf(v2, x2, ap2); ag2 = fmaf(v2 * m2, x2, ag2);
        ap3 = fmaf(v3, x3, ap3); ag3 = fmaf(v3 * m3, x3, ag3);
    }
    for (; j < e; ++j) {
        int c0 = colv[j];
        float x0 = bf2f(g_xbf[c0 * 64 + lane]);
        float v0 = vals[j], m0 = g_mt0[j];
        ap0 = fmaf(v0, x0, ap0); ag0 = fmaf(v0 * m0, x0, ag0);
    }
    float ap = (ap0 + ap1) + (ap2 + ap3);
    float ag = (ag0 + ag1) + (ag2 + ag3);
    unsigned int pk = (unsigned int)f2bf(ap) | ((unsigned int)f2bf(ag) << 16);
    *(unsigned int*)&g_ABh[w * 128 + 2 * lane] = pk;

    // sm0 epilogue (fp32 cur1)
    float h = sb[lane];
#pragma unroll
    for (int k = 0; k < 64; ++k)
        h = fmaf(__shfl(ap, k, 64), sW[k][lane], h);
    h = fmaxf(h, 0.f);
    float p = h * sw2[lane];
#pragma unroll
    for (int off = 32; off >= 1; off >>= 1) p += __shfl_xor(p, off, 64);
    if (lane == 0) {
        float z = (noise[w] + p + b2[0]) * 2.0f;
        g_sm0[w] = 1.0f / (1.0f + expf(-z));
    }
}

// ---------------------------------------------------------------------------
// S2: fused cur2+t2 via ONE packed 4B gather/edge-lane,
//     + emb_t epilogue + node-MLP epilogue -> sm1.
// ---------------------------------------------------------------------------
__global__ __launch_bounds__(256) void s2_kernel(
    const int* __restrict__ colv,
    const float* __restrict__ vals,
    const float* __restrict__ x,
    const float* __restrict__ W1,
    const float* __restrict__ b1,
    const float* __restrict__ W2,
    const float* __restrict__ b2,
    const float* __restrict__ noise,
    float* __restrict__ emb_t,
    int n)
{
    __shared__ float sW[64][65];
    __shared__ float sb[64], sw2[64];
    int tid = threadIdx.x;
    for (int idx = tid; idx < 4096; idx += 256)
        sW[idx >> 6][idx & 63] = W1[idx];
    if (tid < 64) { sb[tid] = b1[tid]; sw2[tid] = W2[tid]; }
    __syncthreads();

    int w = (blockIdx.x * 256 + tid) >> 6;
    int lane = tid & 63;
    int s = g_rowptr[w], e = g_rowptr[w + 1];
    float ac0 = 0.f, ac1 = 0.f, ac2 = 0.f, ac3 = 0.f;
    float at0 = 0.f, at1 = 0.f, at2 = 0.f, at3 = 0.f;
    int j = s;
    for (; j + 3 < e; j += 4) {
        int c0 = colv[j], c1 = colv[j + 1], c2 = colv[j + 2], c3 = colv[j + 3];
        unsigned int u0 = *(const unsigned int*)&g_ABh[c0 * 128 + 2 * lane];
        unsigned int u1 = *(const unsigned int*)&g_ABh[c1 * 128 + 2 * lane];
        unsigned int u2 = *(const unsigned int*)&g_ABh[c2 * 128 + 2 * lane];
        unsigned int u3 = *(const unsigned int*)&g_ABh[c3 * 128 + 2 * lane];
        float v0 = vals[j], v1 = vals[j + 1], v2 = vals[j + 2], v3 = vals[j + 3];
        float m0 = g_mt1[j], m1 = g_mt1[j + 1], m2 = g_mt1[j + 2], m3 = g_mt1[j + 3];
        ac0 = fmaf(v0, bf2f_lo(u0), ac0); at0 = fmaf(v0 * m0, bf2f_hi(u0), at0);
        ac1 = fmaf(v1, bf2f_lo(u1), ac1); at1 = fmaf(v1 * m1, bf2f_hi(u1), at1);
        ac2 = fmaf(v2, bf2f_lo(u2), ac2); at2 = fmaf(v2 * m2, bf2f_hi(u2), at2);
        ac3 = fmaf(v3, bf2f_lo(u3), ac3); at3 = fmaf(v3 * m3, bf2f_hi(u3), at3);
    }
    for (; j < e; ++j) {
        int c0 = colv[j];
        unsigned int u0 = *(const unsigned int*)&g_ABh[c0 * 128 + 2 * lane];
        float v0 = vals[j], m0 = g_mt1[j];
        ac0 = fmaf(v0, bf2f_lo(u0), ac0); at0 = fmaf(v0 * m0, bf2f_hi(u0), at0);
    }
    float ac = (ac0 + ac1) + (ac2 + ac3);
    float at = (at0 + at1) + (at2 + at3);
    int o = w * 64 + lane;
    unsigned int uw = *(const unsigned int*)&g_ABh[w * 128 + 2 * lane];
    emb_t[o] = (x[o] + bf2f_hi(uw) + at) * (1.0f / 3.0f);

    // sm1 epilogue from cur2 = ac
    float h = sb[lane];
#pragma unroll
    for (int k = 0; k < 64; ++k)
        h = fmaf(__shfl(ac, k, 64), sW[k][lane], h);
    h = fmaxf(h, 0.f);
    float p = h * sw2[lane];
#pragma unroll
    for (int off = 32; off >= 1; off >>= 1) p += __shfl_xor(p, off, 64);
    if (lane == 0) {
        float z = (noise[w] + p + b2[0]) * 2.0f;
        g_sm1[w] = 1.0f / (1.0f + expf(-z));
    }
}

// ---------------------------------------------------------------------------
// SpMM over bf16 h; out16 (bf16) or outavg=(ea+eb+acc)/3 (fp32).
// ---------------------------------------------------------------------------
__global__ __launch_bounds__(256) void spmm_kernel(
    const int* __restrict__ colv,
    const float* __restrict__ vals,
    const unsigned short* __restrict__ h,     // bf16 [n,64]
    unsigned short* __restrict__ out16,       // nullable
    float* __restrict__ outavg,               // nullable
    const float* __restrict__ ea,             // fp32 x
    const unsigned short* __restrict__ eb,    // bf16 c1
    int n)
{
    int w = (blockIdx.x * 256 + threadIdx.x) >> 6;
    int lane = threadIdx.x & 63;
    if (w >= n) return;
    int s = g_rowptr[w], e = g_rowptr[w + 1];
    float a0 = 0.f, a1 = 0.f, a2 = 0.f, a3 = 0.f;
    int j = s;
    for (; j + 3 < e; j += 4) {
        int c0 = colv[j], c1 = colv[j + 1], c2 = colv[j + 2], c3 = colv[j + 3];
        float h0 = bf2f(h[c0 * 64 + lane]);
        float h1 = bf2f(h[c1 * 64 + lane]);
        float h2 = bf2f(h[c2 * 64 + lane]);
        float h3 = bf2f(h[c3 * 64 + lane]);
        a0 = fmaf(vals[j],     h0, a0);
        a1 = fmaf(vals[j + 1], h1, a1);
        a2 = fmaf(vals[j + 2], h2, a2);
        a3 = fmaf(vals[j + 3], h3, a3);
    }
    for (; j < e; ++j)
        a0 = fmaf(vals[j], bf2f(h[colv[j] * 64 + lane]), a0);
    float acc = (a0 + a1) + (a2 + a3);
    int o = w * 64 + lane;
    if (out16) out16[o] = f2bf(acc);
    if (outavg) outavg[o] = (ea[o] + bf2f(eb[o]) + acc) * (1.0f / 3.0f);
}

// ---------------------------------------------------------------------------
// Random-walk mean-pool + gate over bf16 cur -> bf16 out
// ---------------------------------------------------------------------------
__global__ __launch_bounds__(256) void rwgate_kernel(
    const int* __restrict__ rw_col,
    const float* __restrict__ rw_vals,
    const unsigned short* __restrict__ cur,   // bf16
    const float* __restrict__ smask,
    unsigned short* __restrict__ outg,        // bf16
    int n)
{
    int w = (blockIdx.x * 256 + threadIdx.x) >> 6;
    int lane = threadIdx.x & 63;
    if (w >= n) return;
    float mp = 0.f;
    int base = w * WKLEN;
#pragma unroll
    for (int j = 0; j < WKLEN; ++j) {
        int c = rw_col[base + j];
        mp = fmaf(rw_vals[base + j], bf2f(cur[c * 64 + lane]), mp);
    }
    float sm = smask[w];
    float r = sm * bf2f(cur[w * 64 + lane]) + (1.f - sm) * mp;
    outg[w * 64 + lane] = f2bf(r);
}

// ---------------------------------------------------------------------------
// Final scalars
// ---------------------------------------------------------------------------
__global__ __launch_bounds__(256) void finalize_kernel(
    float* __restrict__ out, int n)
{
    __shared__ float red[256];
    float s = 0.f;
    for (int i = threadIdx.x; i < n; i += 256) s += g_sm0[i] + g_sm1[i];
    red[threadIdx.x] = s;
    __syncthreads();
    for (int off = 128; off >= 1; off >>= 1) {
        if (threadIdx.x < off) red[threadIdx.x] += red[threadIdx.x + off];
        __syncthreads();
    }
    if (threadIdx.x == 0) {
        out[6400000] = 0.0f;
        out[6400001] = red[0] / (2.0f * n);
    }
}

extern "C" void kernel_launch(void* const* d_in, const int* in_sizes, int n_in,
                              void* d_out, int out_size, void* d_ws, size_t ws_size,
                              hipStream_t stream)
{
    const float* x    = (const float*)d_in[0];
    const float* vals = (const float*)d_in[1];
    const float* rwv  = (const float*)d_in[2];
    const float* tW1  = (const float*)d_in[3];
    const float* tb1  = (const float*)d_in[4];
    const float* tW2  = (const float*)d_in[5];
    const float* tb2  = (const float*)d_in[6];
    const float* sW1  = (const float*)d_in[7];
    const float* sb1  = (const float*)d_in[8];
    const float* sW2  = (const float*)d_in[9];
    const float* sb2  = (const float*)d_in[10];
    const float* tnz  = (const float*)d_in[11];
    const float* snz  = (const float*)d_in[12];
    const int* row   = (const int*)d_in[13];
    const int* colv  = (const int*)d_in[14];
    const int* rwcol = (const int*)d_in[16];

    const int n = NNODES;
    const int nE = in_sizes[1];

    float* out   = (float*)d_out;
    float* emb_t = out;
    float* emb_s = out + 3200000;
    float* masko = out + 6400002;

    unsigned short *Ah, *Bh, *xbf;
    hipGetSymbolAddress((void**)&Ah, HIP_SYMBOL(g_Ah));
    hipGetSymbolAddress((void**)&Bh, HIP_SYMBOL(g_Bh));
    hipGetSymbolAddress((void**)&xbf, HIP_SYMBOL(g_xbf));
    float *sm0p, *sm1p;
    hipGetSymbolAddress((void**)&sm0p, HIP_SYMBOL(g_sm0));
    hipGetSymbolAddress((void**)&sm1p, HIP_SYMBOL(g_sm1));

    // K0: row_ptr
    rowptr_kernel<<<(n + 256) / 256, 256, 0, stream>>>(row, n, nE);
    // K1: prep (x->bf16, W1 swizzle)
    prep_kernel<<<1563, 256, 0, stream>>>(x, tW1, n * EDIM / 8);
    // K2: edge MLP -> g_mt0, g_mt1, mask output
    edge_mlp_kernel<<<nE / 256, 256, 0, stream>>>(tb1, tW2, tb2, tnz,
                                                  row, colv, masko, nE);
    // S1: cur1,t1 packed + sm0
    s1_kernel<<<(n * 64) / 256, 256, 0, stream>>>(colv, vals,
                                                  sW1, sb1, sW2, sb2, snz, n);
    // S2: emb_t + sm1
    s2_kernel<<<(n * 64) / 256, 256, 0, stream>>>(colv, vals, x,
                                                  sW1 + 4096, sb1 + 64, sW2 + 64,
                                                  sb2 + 1, snz + n, emb_t, n);
    // K9: Ah = g0 = sm0*x + (1-sm0)*rwpool(x)      [bf16]
    rwgate_kernel<<<(n * 64) / 256, 256, 0, stream>>>(rwcol, rwv, xbf, sm0p, Ah, n);
    // K10: Bh = c1 = spmm(vals, g0)                [bf16]
    spmm_kernel<<<(n * 64) / 256, 256, 0, stream>>>(colv, vals, Ah,
                                                    Bh, nullptr, nullptr, nullptr, n);
    // K11: Ah = g1 = sm1*c1 + (1-sm1)*rwpool(c1)   [bf16]
    rwgate_kernel<<<(n * 64) / 256, 256, 0, stream>>>(rwcol, rwv, Bh, sm1p, Ah, n);
    // K12: emb_s = (x + c1 + spmm(vals, g1)) / 3
    spmm_kernel<<<(n * 64) / 256, 256, 0, stream>>>(colv, vals, Ah,
                                                    nullptr, emb_s, x, Bh, n);
    // K13: scalars
    finalize_kernel<<<1, 256, 0, stream>>>(out, n);
}

// Round 7
// 431.222 us; speedup vs baseline: 1.6391x; 1.1812x over previous
//
#include <hip/hip_runtime.h>

#define NNODES 50000
#define EDIM 64
#define WKLEN 9
#define NEDGE 800000
#define NPAD (NNODES + 64)

using bf16x8 = __attribute__((ext_vector_type(8))) __bf16;
using f32x4  = __attribute__((ext_vector_type(4))) float;

// ---- static device scratch ----
__device__ __align__(256) unsigned short g_xbf[NNODES * EDIM];   // bf16 x
__device__ __align__(256) unsigned short g_ABh[NNODES * 128];    // packed (cur1,t1)
__device__ __align__(256) unsigned short g_c1h[NPAD * EDIM];     // cur1 bf16 (nm0)
__device__ __align__(256) unsigned short g_c2h[NPAD * EDIM];     // cur2 bf16 (nm1)
__device__ __align__(256) unsigned short g_g0h[NNODES * EDIM];   // g0 then g1
__device__ __align__(256) unsigned short g_sc1h[NNODES * EDIM];  // s-branch c1
__device__ __align__(256) float g_mt0[NEDGE];
__device__ __align__(256) float g_mt1[NEDGE];
__device__ __align__(256) float g_sm0[NNODES];
__device__ __align__(256) float g_sm1[NNODES];
__device__ __align__(256) int   g_rowptr[NNODES + 1];
__device__ __align__(256) unsigned short g_Bswz[2048 * 8];  // edge-MLP W1 frags
__device__ __align__(256) unsigned short g_Sswz[1024 * 8];  // node-MLP W1 frags

__device__ __forceinline__ unsigned short f2bf(float f) {
    union { float f; unsigned int i; } v;
    v.f = f;
    unsigned int r = v.i + 0x7FFFu + ((v.i >> 16) & 1u);
    return (unsigned short)(r >> 16);
}
__device__ __forceinline__ float bf2f_lo(unsigned int u) {
    union { unsigned int i; float f; } v; v.i = u << 16; return v.f;
}
__device__ __forceinline__ float bf2f_hi(unsigned int u) {
    union { unsigned int i; float f; } v; v.i = u & 0xFFFF0000u; return v.f;
}

// ---------------------------------------------------------------------------
// L1: misc — x->bf16 | rowptr | W1 edge swizzle | W1 node swizzle
// ---------------------------------------------------------------------------
__global__ __launch_bounds__(256) void misc_kernel(
    const float* __restrict__ x, const float* __restrict__ tW1,
    const float* __restrict__ sW1, const int* __restrict__ row,
    int n, int nE)
{
    int bid = blockIdx.x, tid = threadIdx.x;
    if (bid < 1563) {
        int i = bid * 256 + tid;
        if (i < NNODES * EDIM / 8) {
            const float* src = x + i * 8;
            union { unsigned short s[8]; uint4 q; } u;
#pragma unroll
            for (int j = 0; j < 8; ++j) u.s[j] = f2bf(src[j]);
            *(uint4*)&g_xbf[i * 8] = u.q;
        }
    } else if (bid < 1759) {
        int i = (bid - 1563) * 256 + tid;
        if (i > n) return;
        int lo = 0, hi = nE;
        while (lo < hi) {
            int mid = (lo + hi) >> 1;
            if (row[mid] < i) lo = mid + 1; else hi = mid;
        }
        g_rowptr[i] = lo;
    } else if (bid < 1767) {
        int t = (bid - 1759) * 256 + tid;  // 0..2047
        int li = t >> 10, ks = (t >> 8) & 3, nn = (t >> 6) & 3, ln = t & 63;
        int q = ln >> 4, mcl = ln & 15;
        union { unsigned short s[8]; uint4 q4; } u;
#pragma unroll
        for (int j = 0; j < 8; ++j)
            u.s[j] = f2bf(tW1[li * 8192 + (ks * 32 + q * 8 + j) * 64 + nn * 16 + mcl]);
        *(uint4*)&g_Bswz[t * 8] = u.q4;
    } else {
        int t = (bid - 1767) * 256 + tid;  // 0..1023
        int li = t >> 9, ks = (t >> 8) & 1, nn = (t >> 6) & 3, ln = t & 63;
        int q = ln >> 4, mcl = ln & 15;
        union { unsigned short s[8]; uint4 q4; } u;
#pragma unroll
        for (int j = 0; j < 8; ++j)
            u.s[j] = f2bf(sW1[li * 4096 + (ks * 32 + q * 8 + j) * 64 + nn * 16 + mcl]);
        *(uint4*)&g_Sswz[t * 8] = u.q4;
    }
}

// ---------------------------------------------------------------------------
// L2: edge MLP via MFMA — B staged in LDS (read JIT), A gathered from g_xbf.
// ---------------------------------------------------------------------------
__global__ __launch_bounds__(256) void edge_mlp_kernel(
    const float* __restrict__ tb1,
    const float* __restrict__ tW2,
    const float* __restrict__ tb2,
    const float* __restrict__ tnoise,
    const int* __restrict__ row,
    const int* __restrict__ col,
    float* __restrict__ mask_out,
    int nE)
{
    __shared__ uint4 sB[2048];  // 32 KB: all 32 W1 fragments x 64 lanes
    const int tid = threadIdx.x;
    for (int t = tid; t < 2048; t += 256) sB[t] = ((const uint4*)g_Bswz)[t];

    const int wave = tid >> 6, lane = tid & 63;
    const int mc = lane & 15, quad = lane >> 4;
    float b1v[2][4], w2v[2][4];
#pragma unroll
    for (int i = 0; i < 2; ++i)
#pragma unroll
        for (int nn = 0; nn < 4; ++nn) {
            b1v[i][nn] = tb1[i * 64 + nn * 16 + mc];
            w2v[i][nn] = tW2[i * 64 + nn * 16 + mc];
        }
    const float b2v[2] = { tb2[0], tb2[1] };
    const int base = blockIdx.x * 256;
    __syncthreads();

    auto loadA = [&](int g, bf16x8* af) {
        int e = base + g * 64 + wave * 16 + mc;
        int rn = row[e], cn = col[e];
        const unsigned short* pr = g_xbf + rn * 64 + quad * 8;
        const unsigned short* pc = g_xbf + cn * 64 + quad * 8;
        af[0] = *(const bf16x8*)pr;
        af[1] = *(const bf16x8*)(pr + 32);
        af[2] = *(const bf16x8*)pc;
        af[3] = *(const bf16x8*)(pc + 32);
    };

    bf16x8 afC[4], afN[4];
    loadA(0, afC);
    for (int g = 0; g < 4; ++g) {
        if (g < 3) loadA(g + 1, afN);
#pragma unroll
        for (int i = 0; i < 2; ++i) {
            f32x4 acc[4];
            const f32x4 zero = {0.f, 0.f, 0.f, 0.f};
#pragma unroll
            for (int nn = 0; nn < 4; ++nn) acc[nn] = zero;
#pragma unroll
            for (int ks = 0; ks < 4; ++ks)
#pragma unroll
                for (int nn = 0; nn < 4; ++nn) {
                    bf16x8 b = *(const bf16x8*)&sB[(i * 16 + ks * 4 + nn) * 64 + lane];
                    acc[nn] = __builtin_amdgcn_mfma_f32_16x16x32_bf16(
                        afC[ks], b, acc[nn], 0, 0, 0);
                }
            float p[4];
#pragma unroll
            for (int r = 0; r < 4; ++r) {
                float s = 0.f;
#pragma unroll
                for (int nn = 0; nn < 4; ++nn) {
                    float h = acc[nn][r] + b1v[i][nn];
                    s = fmaf(fmaxf(h, 0.f), w2v[i][nn], s);
                }
                p[r] = s;
            }
#pragma unroll
            for (int off = 8; off >= 1; off >>= 1)
#pragma unroll
                for (int r = 0; r < 4; ++r) p[r] += __shfl_xor(p[r], off, 64);
            if (mc == 0) {
                const float* nz = tnoise + i * nE;
                float* mo = (i == 0) ? g_mt0 : g_mt1;
#pragma unroll
                for (int r = 0; r < 4; ++r) {
                    int e = base + g * 64 + wave * 16 + quad * 4 + r;
                    float z = (nz[e] + p[r] + b2v[i]) * 2.0f;
                    float mval = 1.0f / (1.0f + expf(-z));
                    mo[e] = mval;
                    if (i == 1) mask_out[e] = mval;
                }
            }
        }
#pragma unroll
        for (int ks = 0; ks < 4; ++ks) afC[ks] = afN[ks];
    }
}

// ---------------------------------------------------------------------------
// node-MLP via MFMA: 16 nodes/wave, K=64, hidden 64, dot W2, sigmoid -> sm
// ---------------------------------------------------------------------------
__device__ __forceinline__ void nm_body(
    int bid, const unsigned short* __restrict__ cur, int li,
    const float* __restrict__ b1, const float* __restrict__ W2,
    const float* __restrict__ b2, const float* __restrict__ noise,
    float* __restrict__ smout, int n)
{
    int tid = threadIdx.x;
    int wave = tid >> 6, lane = tid & 63;
    int mc = lane & 15, quad = lane >> 4;
    int nb = bid * 64 + wave * 16;
    const unsigned short* basep = cur + (nb + mc) * 64 + quad * 8;
    bf16x8 af0 = *(const bf16x8*)basep;
    bf16x8 af1 = *(const bf16x8*)(basep + 32);
    f32x4 acc[4];
    const f32x4 zero = {0.f, 0.f, 0.f, 0.f};
#pragma unroll
    for (int nn = 0; nn < 4; ++nn) acc[nn] = zero;
#pragma unroll
    for (int nn = 0; nn < 4; ++nn) {
        bf16x8 b0 = *(const bf16x8*)&g_Sswz[((li * 8 + nn) * 64 + lane) * 8];
        bf16x8 b1f = *(const bf16x8*)&g_Sswz[((li * 8 + 4 + nn) * 64 + lane) * 8];
        acc[nn] = __builtin_amdgcn_mfma_f32_16x16x32_bf16(af0, b0, acc[nn], 0, 0, 0);
        acc[nn] = __builtin_amdgcn_mfma_f32_16x16x32_bf16(af1, b1f, acc[nn], 0, 0, 0);
    }
    float p[4];
#pragma unroll
    for (int r = 0; r < 4; ++r) {
        float s = 0.f;
#pragma unroll
        for (int nn = 0; nn < 4; ++nn) {
            float h = acc[nn][r] + b1[nn * 16 + mc];
            s = fmaf(fmaxf(h, 0.f), W2[nn * 16 + mc], s);
        }
        p[r] = s;
    }
#pragma unroll
    for (int off = 8; off >= 1; off >>= 1)
#pragma unroll
        for (int r = 0; r < 4; ++r) p[r] += __shfl_xor(p[r], off, 64);
    if (mc == 0) {
        float b2v = b2[0];
#pragma unroll
        for (int r = 0; r < 4; ++r) {
            int node = nb + quad * 4 + r;
            if (node < n) {
                float z = (noise[node] + p[r] + b2v) * 2.0f;
                smout[node] = 1.0f / (1.0f + expf(-z));
            }
        }
    }
}

// ---------------------------------------------------------------------------
// L3: s1 — cur1 + t1 in one gather pass (half-wave split), packed + plain out
// ---------------------------------------------------------------------------
__global__ __launch_bounds__(256) void s1_kernel(
    const int* __restrict__ colv, const float* __restrict__ vals, int n)
{
    int w = (blockIdx.x * 256 + threadIdx.x) >> 6;
    int lane = threadIdx.x & 63;
    int el = lane >> 5, d2 = lane & 31;
    int s = g_rowptr[w], e = g_rowptr[w + 1];
    float p0 = 0.f, p1 = 0.f, q0 = 0.f, q1 = 0.f;
    float P0 = 0.f, P1 = 0.f, Q0 = 0.f, Q1 = 0.f;
    int j = s + el;
    for (; j + 2 < e; j += 4) {
        int cA = colv[j];      float vA = vals[j];     float mA = g_mt0[j];
        int cB = colv[j + 2];  float vB = vals[j + 2]; float mB = g_mt0[j + 2];
        unsigned uA = *(const unsigned*)&g_xbf[cA * 64 + 2 * d2];
        unsigned uB = *(const unsigned*)&g_xbf[cB * 64 + 2 * d2];
        float a0 = bf2f_lo(uA), a1 = bf2f_hi(uA);
        float bb0 = bf2f_lo(uB), bb1 = bf2f_hi(uB);
        float vmA = vA * mA, vmB = vB * mB;
        p0 = fmaf(vA, a0, p0);  p1 = fmaf(vA, a1, p1);
        q0 = fmaf(vmA, a0, q0); q1 = fmaf(vmA, a1, q1);
        P0 = fmaf(vB, bb0, P0);  P1 = fmaf(vB, bb1, P1);
        Q0 = fmaf(vmB, bb0, Q0); Q1 = fmaf(vmB, bb1, Q1);
    }
    for (; j < e; j += 2) {
        int c = colv[j]; float v = vals[j], m = g_mt0[j];
        unsigned u = *(const unsigned*)&g_xbf[c * 64 + 2 * d2];
        float a0 = bf2f_lo(u), a1 = bf2f_hi(u);
        float vm = v * m;
        p0 = fmaf(v, a0, p0);  p1 = fmaf(v, a1, p1);
        q0 = fmaf(vm, a0, q0); q1 = fmaf(vm, a1, q1);
    }
    p0 += P0; p1 += P1; q0 += Q0; q1 += Q1;
    p0 += __shfl_xor(p0, 32, 64); p1 += __shfl_xor(p1, 32, 64);
    q0 += __shfl_xor(q0, 32, 64); q1 += __shfl_xor(q1, 32, 64);
    if (el == 0) {
        uint2 pk;
        pk.x = (unsigned)f2bf(p0) | ((unsigned)f2bf(q0) << 16);
        pk.y = (unsigned)f2bf(p1) | ((unsigned)f2bf(q1) << 16);
        *(uint2*)&g_ABh[w * 128 + 4 * d2] = pk;
        *(unsigned*)&g_c1h[w * 64 + 2 * d2] =
            (unsigned)f2bf(p0) | ((unsigned)f2bf(p1) << 16);
    }
}

// ---------------------------------------------------------------------------
// L4: s2 (cur2+t2+emb_t, cur2h out) merged with nm0 (sm0 from cur1h)
// ---------------------------------------------------------------------------
__global__ __launch_bounds__(256) void s2_nm0_kernel(
    const int* __restrict__ colv, const float* __restrict__ vals,
    const float* __restrict__ x, float* __restrict__ emb_t,
    const float* __restrict__ sb1, const float* __restrict__ sW2,
    const float* __restrict__ sb2, const float* __restrict__ snz, int n)
{
    if (blockIdx.x >= 12500) {
        nm_body(blockIdx.x - 12500, g_c1h, 0, sb1, sW2, sb2, snz, g_sm0, n);
        return;
    }
    int w = (blockIdx.x * 256 + threadIdx.x) >> 6;
    int lane = threadIdx.x & 63;
    int el = lane >> 5, d2 = lane & 31;
    int s = g_rowptr[w], e = g_rowptr[w + 1];
    float c0 = 0.f, c1 = 0.f, t0 = 0.f, t1 = 0.f;
    float C0 = 0.f, C1 = 0.f, T0 = 0.f, T1 = 0.f;
    int j = s + el;
    for (; j + 2 < e; j += 4) {
        int cA = colv[j];      float vA = vals[j];     float mA = g_mt1[j];
        int cB = colv[j + 2];  float vB = vals[j + 2]; float mB = g_mt1[j + 2];
        uint2 UA = *(const uint2*)&g_ABh[cA * 128 + 4 * d2];
        uint2 UB = *(const uint2*)&g_ABh[cB * 128 + 4 * d2];
        float vmA = vA * mA, vmB = vB * mB;
        c0 = fmaf(vA, bf2f_lo(UA.x), c0); t0 = fmaf(vmA, bf2f_hi(UA.x), t0);
        c1 = fmaf(vA, bf2f_lo(UA.y), c1); t1 = fmaf(vmA, bf2f_hi(UA.y), t1);
        C0 = fmaf(vB, bf2f_lo(UB.x), C0); T0 = fmaf(vmB, bf2f_hi(UB.x), T0);
        C1 = fmaf(vB, bf2f_lo(UB.y), C1); T1 = fmaf(vmB, bf2f_hi(UB.y), T1);
    }
    for (; j < e; j += 2) {
        int c = colv[j]; float v = vals[j], m = g_mt1[j];
        uint2 U = *(const uint2*)&g_ABh[c * 128 + 4 * d2];
        float vm = v * m;
        c0 = fmaf(v, bf2f_lo(U.x), c0); t0 = fmaf(vm, bf2f_hi(U.x), t0);
        c1 = fmaf(v, bf2f_lo(U.y), c1); t1 = fmaf(vm, bf2f_hi(U.y), t1);
    }
    c0 += C0; c1 += C1; t0 += T0; t1 += T1;
    c0 += __shfl_xor(c0, 32, 64); c1 += __shfl_xor(c1, 32, 64);
    t0 += __shfl_xor(t0, 32, 64); t1 += __shfl_xor(t1, 32, 64);
    if (el == 0) {
        int o2 = w * 64 + 2 * d2;
        uint2 U2 = *(const uint2*)&g_ABh[w * 128 + 4 * d2];
        float2 et;
        et.x = (x[o2]     + bf2f_hi(U2.x) + t0) * (1.0f / 3.0f);
        et.y = (x[o2 + 1] + bf2f_hi(U2.y) + t1) * (1.0f / 3.0f);
        *(float2*)&emb_t[o2] = et;
        *(unsigned*)&g_c2h[o2] = (unsigned)f2bf(c0) | ((unsigned)f2bf(c1) << 16);
    }
}

// ---------------------------------------------------------------------------
// rwgate body (half-wave split over the 9 walk entries)
// ---------------------------------------------------------------------------
__device__ __forceinline__ void rw_body(
    int bid, const int* __restrict__ rw_col, const float* __restrict__ rwv,
    const unsigned short* __restrict__ cur, const float* __restrict__ smask,
    unsigned short* __restrict__ outg)
{
    int w = (bid * 256 + threadIdx.x) >> 6;
    int lane = threadIdx.x & 63;
    int el = lane >> 5, d2 = lane & 31;
    int base = w * WKLEN;
    float a0 = 0.f, a1 = 0.f;
    for (int j = el; j < WKLEN; j += 2) {
        int c = rw_col[base + j];
        float v = rwv[base + j];
        unsigned u = *(const unsigned*)&cur[c * 64 + 2 * d2];
        a0 = fmaf(v, bf2f_lo(u), a0);
        a1 = fmaf(v, bf2f_hi(u), a1);
    }
    a0 += __shfl_xor(a0, 32, 64);
    a1 += __shfl_xor(a1, 32, 64);
    if (el == 0) {
        float sm = smask[w];
        unsigned u = *(const unsigned*)&cur[w * 64 + 2 * d2];
        float r0 = sm * bf2f_lo(u) + (1.f - sm) * a0;
        float r1 = sm * bf2f_hi(u) + (1.f - sm) * a1;
        *(unsigned*)&outg[w * 64 + 2 * d2] =
            (unsigned)f2bf(r0) | ((unsigned)f2bf(r1) << 16);
    }
}

// ---------------------------------------------------------------------------
// L5: rwgate(x->g0) merged with nm1 (sm1 from cur2h)
// ---------------------------------------------------------------------------
__global__ __launch_bounds__(256) void rw0_nm1_kernel(
    const int* __restrict__ rw_col, const float* __restrict__ rwv,
    const float* __restrict__ sb1, const float* __restrict__ sW2,
    const float* __restrict__ sb2, const float* __restrict__ snz, int n)
{
    if (blockIdx.x >= 12500) {
        nm_body(blockIdx.x - 12500, g_c2h, 1, sb1, sW2, sb2, snz, g_sm1, n);
        return;
    }
    rw_body(blockIdx.x, rw_col, rwv, g_xbf, g_sm0, g_g0h);
}

// ---------------------------------------------------------------------------
// L6: spmm c1 = spmm(vals, g0)  (bf16 in/out, half-wave split)
// ---------------------------------------------------------------------------
__global__ __launch_bounds__(256) void spmm10_kernel(
    const int* __restrict__ colv, const float* __restrict__ vals, int n)
{
    int w = (blockIdx.x * 256 + threadIdx.x) >> 6;
    int lane = threadIdx.x & 63;
    int el = lane >> 5, d2 = lane & 31;
    int s = g_rowptr[w], e = g_rowptr[w + 1];
    float a0 = 0.f, a1 = 0.f, A0 = 0.f, A1 = 0.f;
    int j = s + el;
    for (; j + 2 < e; j += 4) {
        int cA = colv[j];     float vA = vals[j];
        int cB = colv[j + 2]; float vB = vals[j + 2];
        unsigned uA = *(const unsigned*)&g_g0h[cA * 64 + 2 * d2];
        unsigned uB = *(const unsigned*)&g_g0h[cB * 64 + 2 * d2];
        a0 = fmaf(vA, bf2f_lo(uA), a0); a1 = fmaf(vA, bf2f_hi(uA), a1);
        A0 = fmaf(vB, bf2f_lo(uB), A0); A1 = fmaf(vB, bf2f_hi(uB), A1);
    }
    for (; j < e; j += 2) {
        int c = colv[j]; float v = vals[j];
        unsigned u = *(const unsigned*)&g_g0h[c * 64 + 2 * d2];
        a0 = fmaf(v, bf2f_lo(u), a0); a1 = fmaf(v, bf2f_hi(u), a1);
    }
    a0 += A0; a1 += A1;
    a0 += __shfl_xor(a0, 32, 64); a1 += __shfl_xor(a1, 32, 64);
    if (el == 0)
        *(unsigned*)&g_sc1h[w * 64 + 2 * d2] =
            (unsigned)f2bf(a0) | ((unsigned)f2bf(a1) << 16);
}

// ---------------------------------------------------------------------------
// L7: rwgate(c1 -> g1)
// ---------------------------------------------------------------------------
__global__ __launch_bounds__(256) void rw1_kernel(
    const int* __restrict__ rw_col, const float* __restrict__ rwv)
{
    rw_body(blockIdx.x, rw_col, rwv, g_sc1h, g_sm1, g_g0h);
}

// ---------------------------------------------------------------------------
// L8: emb_s = (x + c1 + spmm(vals, g1))/3, merged with finalize
// ---------------------------------------------------------------------------
__global__ __launch_bounds__(256) void spmm12_fin_kernel(
    const int* __restrict__ colv, const float* __restrict__ vals,
    const float* __restrict__ x, float* __restrict__ emb_s,
    float* __restrict__ out, int n)
{
    if (blockIdx.x >= 12500) {
        __shared__ float red[256];
        float s = 0.f;
        for (int i = threadIdx.x; i < n; i += 256) s += g_sm0[i] + g_sm1[i];
        red[threadIdx.x] = s;
        __syncthreads();
        for (int off = 128; off >= 1; off >>= 1) {
            if (threadIdx.x < off) red[threadIdx.x] += red[threadIdx.x + off];
            __syncthreads();
        }
        if (threadIdx.x == 0) {
            out[6400000] = 0.0f;
            out[6400001] = red[0] / (2.0f * n);
        }
        return;
    }
    int w = (blockIdx.x * 256 + threadIdx.x) >> 6;
    int lane = threadIdx.x & 63;
    int el = lane >> 5, d2 = lane & 31;
    int s = g_rowptr[w], e = g_rowptr[w + 1];
    float a0 = 0.f, a1 = 0.f, A0 = 0.f, A1 = 0.f;
    int j = s + el;
    for (; j + 2 < e; j += 4) {
        int cA = colv[j];     float vA = vals[j];
        int cB = colv[j + 2]; float vB = vals[j + 2];
        unsigned uA = *(const unsigned*)&g_g0h[cA * 64 + 2 * d2];
        unsigned uB = *(const unsigned*)&g_g0h[cB * 64 + 2 * d2];
        a0 = fmaf(vA, bf2f_lo(uA), a0); a1 = fmaf(vA, bf2f_hi(uA), a1);
        A0 = fmaf(vB, bf2f_lo(uB), A0); A1 = fmaf(vB, bf2f_hi(uB), A1);
    }
    for (; j < e; j += 2) {
        int c = colv[j]; float v = vals[j];
        unsigned u = *(const unsigned*)&g_g0h[c * 64 + 2 * d2];
        a0 = fmaf(v, bf2f_lo(u), a0); a1 = fmaf(v, bf2f_hi(u), a1);
    }
    a0 += A0; a1 += A1;
    a0 += __shfl_xor(a0, 32, 64); a1 += __shfl_xor(a1, 32, 64);
    if (el == 0) {
        int o2 = w * 64 + 2 * d2;
        unsigned uc = *(const unsigned*)&g_sc1h[o2];
        float2 es;
        es.x = (x[o2]     + bf2f_lo(uc) + a0) * (1.0f / 3.0f);
        es.y = (x[o2 + 1] + bf2f_hi(uc) + a1) * (1.0f / 3.0f);
        *(float2*)&emb_s[o2] = es;
    }
}

extern "C" void kernel_launch(void* const* d_in, const int* in_sizes, int n_in,
                              void* d_out, int out_size, void* d_ws, size_t ws_size,
                              hipStream_t stream)
{
    const float* x    = (const float*)d_in[0];
    const float* vals = (const float*)d_in[1];
    const float* rwv  = (const float*)d_in[2];
    const float* tW1  = (const float*)d_in[3];
    const float* tb1  = (const float*)d_in[4];
    const float* tW2  = (const float*)d_in[5];
    const float* tb2  = (const float*)d_in[6];
    const float* sW1  = (const float*)d_in[7];
    const float* sb1  = (const float*)d_in[8];
    const float* sW2  = (const float*)d_in[9];
    const float* sb2  = (const float*)d_in[10];
    const float* tnz  = (const float*)d_in[11];
    const float* snz  = (const float*)d_in[12];
    const int* row   = (const int*)d_in[13];
    const int* colv  = (const int*)d_in[14];
    const int* rwcol = (const int*)d_in[16];

    const int n = NNODES;
    const int nE = in_sizes[1];

    float* out   = (float*)d_out;
    float* emb_t = out;
    float* emb_s = out + 3200000;
    float* masko = out + 6400002;

    // L1: misc prep
    misc_kernel<<<1771, 256, 0, stream>>>(x, tW1, sW1, row, n, nE);
    // L2: edge MLP
    edge_mlp_kernel<<<nE / 256, 256, 0, stream>>>(tb1, tW2, tb2, tnz,
                                                  row, colv, masko, nE);
    // L3: s1 (cur1|t1 packed + cur1h)
    s1_kernel<<<12500, 256, 0, stream>>>(colv, vals, n);
    // L4: s2 (emb_t, cur2h) + nm0 (sm0)
    s2_nm0_kernel<<<12500 + 782, 256, 0, stream>>>(colv, vals, x, emb_t,
                                                   sb1, sW2, sb2, snz, n);
    // L5: rwgate(x->g0) + nm1 (sm1)
    rw0_nm1_kernel<<<12500 + 782, 256, 0, stream>>>(rwcol, rwv,
                                                    sb1 + 64, sW2 + 64, sb2 + 1,
                                                    snz + n, n);
    // L6: c1 = spmm(vals, g0)
    spmm10_kernel<<<12500, 256, 0, stream>>>(colv, vals, n);
    // L7: g1 = rwgate(c1)
    rw1_kernel<<<12500, 256, 0, stream>>>(rwcol, rwv);
    // L8: emb_s + scalars
    spmm12_fin_kernel<<<12501, 256, 0, stream>>>(colv, vals, x, emb_s, out, n);
}

// Round 8
// 408.557 us; speedup vs baseline: 1.7301x; 1.0555x over previous
//
#include <hip/hip_runtime.h>

#define NNODES 50000
#define EDIM 64
#define WKLEN 9
#define NEDGE 800000
#define NPAD (NNODES + 64)

using bf16x8 = __attribute__((ext_vector_type(8))) __bf16;
using f32x4  = __attribute__((ext_vector_type(4))) float;

// ---- static device scratch ----
__device__ __align__(256) unsigned short g_xbf[NPAD * EDIM];     // bf16 x (padded)
__device__ __align__(256) unsigned short g_ABh[NNODES * 128];    // packed (cur1,t1)
__device__ __align__(256) unsigned short g_c1h[NPAD * EDIM];     // cur1 bf16 (nm0)
__device__ __align__(256) unsigned short g_c2h[NPAD * EDIM];     // cur2 bf16 (nm1)
__device__ __align__(256) unsigned short g_g0h[NNODES * EDIM];   // g0 then g1
__device__ __align__(256) unsigned short g_sc1h[NNODES * EDIM];  // s-branch c1
__device__ __align__(256) unsigned short g_Pr[NNODES * 128];     // x@W1top L0|L1
__device__ __align__(256) unsigned short g_Pc[NNODES * 128];     // x@W1bot L0|L1
__device__ __align__(256) float g_mt0[NEDGE];
__device__ __align__(256) float g_mt1[NEDGE];
__device__ __align__(256) float g_sm0[NNODES];
__device__ __align__(256) float g_sm1[NNODES];
__device__ __align__(256) int   g_rowptr[NNODES + 1];
__device__ __align__(256) unsigned short g_Tswz[2048 * 8];  // edge W1-half frags (4 sets)
__device__ __align__(256) unsigned short g_Sswz[1024 * 8];  // node-MLP W1 frags

__device__ __forceinline__ unsigned short f2bf(float f) {
    union { float f; unsigned int i; } v;
    v.f = f;
    unsigned int r = v.i + 0x7FFFu + ((v.i >> 16) & 1u);
    return (unsigned short)(r >> 16);
}
__device__ __forceinline__ float bf2f_lo(unsigned int u) {
    union { unsigned int i; float f; } v; v.i = u << 16; return v.f;
}
__device__ __forceinline__ float bf2f_hi(unsigned int u) {
    union { unsigned int i; float f; } v; v.i = u & 0xFFFF0000u; return v.f;
}

// ---------------------------------------------------------------------------
// L1: misc — x->bf16 | rowptr | W1-half swizzle (edge) | W1 swizzle (node)
// ---------------------------------------------------------------------------
__global__ __launch_bounds__(256) void misc_kernel(
    const float* __restrict__ x, const float* __restrict__ tW1,
    const float* __restrict__ sW1, const int* __restrict__ row,
    int n, int nE)
{
    int bid = blockIdx.x, tid = threadIdx.x;
    if (bid < 1563) {
        int i = bid * 256 + tid;
        if (i < NNODES * EDIM / 8) {
            const float* src = x + i * 8;
            union { unsigned short s[8]; uint4 q; } u;
#pragma unroll
            for (int j = 0; j < 8; ++j) u.s[j] = f2bf(src[j]);
            *(uint4*)&g_xbf[i * 8] = u.q;
        }
    } else if (bid < 1759) {
        int i = (bid - 1563) * 256 + tid;
        if (i > n) return;
        int lo = 0, hi = nE;
        while (lo < hi) {
            int mid = (lo + hi) >> 1;
            if (row[mid] < i) lo = mid + 1; else hi = mid;
        }
        g_rowptr[i] = lo;
    } else if (bid < 1767) {
        // edge W1 halves: set s = li*2+half; frag f = ks*4+nn (ks in 0..1)
        int t = (bid - 1759) * 256 + tid;   // 0..2047
        int s = t >> 9, f = (t >> 6) & 7, ln = t & 63;
        int li = s >> 1, half = s & 1, ks = f >> 2, nn = f & 3;
        int q = ln >> 4, mcl = ln & 15;
        union { unsigned short sv[8]; uint4 q4; } u;
#pragma unroll
        for (int j = 0; j < 8; ++j) {
            int kg = half * 64 + ks * 32 + q * 8 + j;
            u.sv[j] = f2bf(tW1[li * 8192 + kg * 64 + nn * 16 + mcl]);
        }
        *(uint4*)&g_Tswz[t * 8] = u.q4;
    } else {
        int t = (bid - 1767) * 256 + tid;  // 0..1023
        int li = t >> 9, ks = (t >> 8) & 1, nn = (t >> 6) & 3, ln = t & 63;
        int q = ln >> 4, mcl = ln & 15;
        union { unsigned short sv[8]; uint4 q4; } u;
#pragma unroll
        for (int j = 0; j < 8; ++j)
            u.sv[j] = f2bf(sW1[li * 4096 + (ks * 32 + q * 8 + j) * 64 + nn * 16 + mcl]);
        *(uint4*)&g_Sswz[t * 8] = u.q4;
    }
}

// ---------------------------------------------------------------------------
// L2a: prep2 — P = X @ W1_half for 4 sets via MFMA, bf16 packed out.
// ---------------------------------------------------------------------------
__global__ __launch_bounds__(256) void prep2_kernel(int n)
{
    int tid = threadIdx.x;
    int wave = tid >> 6, lane = tid & 63;
    int mc = lane & 15, quad = lane >> 4;
    int nb = blockIdx.x * 64 + wave * 16;
    const unsigned short* bp = g_xbf + (nb + mc) * 64 + quad * 8;
    bf16x8 af0 = *(const bf16x8*)bp;
    bf16x8 af1 = *(const bf16x8*)(bp + 32);
    const f32x4 zero = {0.f, 0.f, 0.f, 0.f};
#pragma unroll
    for (int s = 0; s < 4; ++s) {
        int li = s >> 1, half = s & 1;
        f32x4 acc[4];
#pragma unroll
        for (int nn = 0; nn < 4; ++nn) acc[nn] = zero;
#pragma unroll
        for (int nn = 0; nn < 4; ++nn) {
            bf16x8 b0 = *(const bf16x8*)&g_Tswz[((s * 8 + nn) * 64 + lane) * 8];
            bf16x8 b1 = *(const bf16x8*)&g_Tswz[((s * 8 + 4 + nn) * 64 + lane) * 8];
            acc[nn] = __builtin_amdgcn_mfma_f32_16x16x32_bf16(af0, b0, acc[nn], 0, 0, 0);
            acc[nn] = __builtin_amdgcn_mfma_f32_16x16x32_bf16(af1, b1, acc[nn], 0, 0, 0);
        }
        unsigned short* dst = half ? g_Pc : g_Pr;
#pragma unroll
        for (int nn = 0; nn < 4; ++nn)
#pragma unroll
            for (int r = 0; r < 4; ++r) {
                int node = nb + quad * 4 + r;
                if (node < n)
                    dst[node * 128 + li * 64 + nn * 16 + mc] = f2bf(acc[nn][r]);
            }
    }
}

// ---------------------------------------------------------------------------
// L2b: edge masks — wave = 8 edges x 8 lanes x 8 dims; no MFMA, no LDS.
// ---------------------------------------------------------------------------
__global__ __launch_bounds__(256) void edge_mask_kernel(
    const float* __restrict__ tb1, const float* __restrict__ tW2,
    const float* __restrict__ tb2, const float* __restrict__ tnoise,
    const int* __restrict__ row, const int* __restrict__ col,
    float* __restrict__ mask_out, int nE)
{
    int tid = threadIdx.x;
    int lane = tid & 63;
    int sub = lane & 7;          // dim octet
    int eg = lane >> 3;          // edge within wave
    int wv = (blockIdx.x * 256 + tid) >> 6;
    int e = wv * 8 + eg;

    float b1_0[8], b1_1[8], w2_0[8], w2_1[8];
    *(float4*)&b1_0[0] = *(const float4*)&tb1[sub * 8];
    *(float4*)&b1_0[4] = *(const float4*)&tb1[sub * 8 + 4];
    *(float4*)&b1_1[0] = *(const float4*)&tb1[64 + sub * 8];
    *(float4*)&b1_1[4] = *(const float4*)&tb1[64 + sub * 8 + 4];
    *(float4*)&w2_0[0] = *(const float4*)&tW2[sub * 8];
    *(float4*)&w2_0[4] = *(const float4*)&tW2[sub * 8 + 4];
    *(float4*)&w2_1[0] = *(const float4*)&tW2[64 + sub * 8];
    *(float4*)&w2_1[4] = *(const float4*)&tW2[64 + sub * 8 + 4];

    int rn = row[e], cn = col[e];
    uint4 qr0 = *(const uint4*)&g_Pr[rn * 128 + sub * 8];
    uint4 qr1 = *(const uint4*)&g_Pr[rn * 128 + 64 + sub * 8];
    uint4 qc0 = *(const uint4*)&g_Pc[cn * 128 + sub * 8];
    uint4 qc1 = *(const uint4*)&g_Pc[cn * 128 + 64 + sub * 8];

    float p0 = 0.f, p1 = 0.f;
    unsigned r0[4] = {qr0.x, qr0.y, qr0.z, qr0.w};
    unsigned r1[4] = {qr1.x, qr1.y, qr1.z, qr1.w};
    unsigned c0[4] = {qc0.x, qc0.y, qc0.z, qc0.w};
    unsigned c1[4] = {qc1.x, qc1.y, qc1.z, qc1.w};
#pragma unroll
    for (int k = 0; k < 4; ++k) {
        float hA = fmaxf(bf2f_lo(r0[k]) + bf2f_lo(c0[k]) + b1_0[2 * k], 0.f);
        float hB = fmaxf(bf2f_hi(r0[k]) + bf2f_hi(c0[k]) + b1_0[2 * k + 1], 0.f);
        p0 = fmaf(hA, w2_0[2 * k], p0);
        p0 = fmaf(hB, w2_0[2 * k + 1], p0);
        float gA = fmaxf(bf2f_lo(r1[k]) + bf2f_lo(c1[k]) + b1_1[2 * k], 0.f);
        float gB = fmaxf(bf2f_hi(r1[k]) + bf2f_hi(c1[k]) + b1_1[2 * k + 1], 0.f);
        p1 = fmaf(gA, w2_1[2 * k], p1);
        p1 = fmaf(gB, w2_1[2 * k + 1], p1);
    }
#pragma unroll
    for (int off = 1; off <= 4; off <<= 1) {
        p0 += __shfl_xor(p0, off, 64);
        p1 += __shfl_xor(p1, off, 64);
    }
    if (sub == 0) {
        float z0 = (tnoise[e] + p0 + tb2[0]) * 2.0f;
        float m0 = 1.0f / (1.0f + expf(-z0));
        g_mt0[e] = m0;
        float z1 = (tnoise[nE + e] + p1 + tb2[1]) * 2.0f;
        float m1 = 1.0f / (1.0f + expf(-z1));
        g_mt1[e] = m1;
        mask_out[e] = m1;
    }
}

// ---------------------------------------------------------------------------
// node-MLP via MFMA: 16 nodes/wave
// ---------------------------------------------------------------------------
__device__ __forceinline__ void nm_body(
    int bid, const unsigned short* __restrict__ cur, int li,
    const float* __restrict__ b1, const float* __restrict__ W2,
    const float* __restrict__ b2, const float* __restrict__ noise,
    float* __restrict__ smout, int n)
{
    int tid = threadIdx.x;
    int wave = tid >> 6, lane = tid & 63;
    int mc = lane & 15, quad = lane >> 4;
    int nb = bid * 64 + wave * 16;
    const unsigned short* basep = cur + (nb + mc) * 64 + quad * 8;
    bf16x8 af0 = *(const bf16x8*)basep;
    bf16x8 af1 = *(const bf16x8*)(basep + 32);
    f32x4 acc[4];
    const f32x4 zero = {0.f, 0.f, 0.f, 0.f};
#pragma unroll
    for (int nn = 0; nn < 4; ++nn) acc[nn] = zero;
#pragma unroll
    for (int nn = 0; nn < 4; ++nn) {
        bf16x8 b0 = *(const bf16x8*)&g_Sswz[((li * 8 + nn) * 64 + lane) * 8];
        bf16x8 b1f = *(const bf16x8*)&g_Sswz[((li * 8 + 4 + nn) * 64 + lane) * 8];
        acc[nn] = __builtin_amdgcn_mfma_f32_16x16x32_bf16(af0, b0, acc[nn], 0, 0, 0);
        acc[nn] = __builtin_amdgcn_mfma_f32_16x16x32_bf16(af1, b1f, acc[nn], 0, 0, 0);
    }
    float p[4];
#pragma unroll
    for (int r = 0; r < 4; ++r) {
        float s = 0.f;
#pragma unroll
        for (int nn = 0; nn < 4; ++nn) {
            float h = acc[nn][r] + b1[nn * 16 + mc];
            s = fmaf(fmaxf(h, 0.f), W2[nn * 16 + mc], s);
        }
        p[r] = s;
    }
#pragma unroll
    for (int off = 8; off >= 1; off >>= 1)
#pragma unroll
        for (int r = 0; r < 4; ++r) p[r] += __shfl_xor(p[r], off, 64);
    if (mc == 0) {
        float b2v = b2[0];
#pragma unroll
        for (int r = 0; r < 4; ++r) {
            int node = nb + quad * 4 + r;
            if (node < n) {
                float z = (noise[node] + p[r] + b2v) * 2.0f;
                smout[node] = 1.0f / (1.0f + expf(-z));
            }
        }
    }
}

// ---------------------------------------------------------------------------
// L3: s1 — cur1 + t1 in one gather pass (half-wave split)
// ---------------------------------------------------------------------------
__global__ __launch_bounds__(256) void s1_kernel(
    const int* __restrict__ colv, const float* __restrict__ vals, int n)
{
    int w = (blockIdx.x * 256 + threadIdx.x) >> 6;
    int lane = threadIdx.x & 63;
    int el = lane >> 5, d2 = lane & 31;
    int s = g_rowptr[w], e = g_rowptr[w + 1];
    float p0 = 0.f, p1 = 0.f, q0 = 0.f, q1 = 0.f;
    float P0 = 0.f, P1 = 0.f, Q0 = 0.f, Q1 = 0.f;
    int j = s + el;
    for (; j + 2 < e; j += 4) {
        int cA = colv[j];      float vA = vals[j];     float mA = g_mt0[j];
        int cB = colv[j + 2];  float vB = vals[j + 2]; float mB = g_mt0[j + 2];
        unsigned uA = *(const unsigned*)&g_xbf[cA * 64 + 2 * d2];
        unsigned uB = *(const unsigned*)&g_xbf[cB * 64 + 2 * d2];
        float a0 = bf2f_lo(uA), a1 = bf2f_hi(uA);
        float bb0 = bf2f_lo(uB), bb1 = bf2f_hi(uB);
        float vmA = vA * mA, vmB = vB * mB;
        p0 = fmaf(vA, a0, p0);  p1 = fmaf(vA, a1, p1);
        q0 = fmaf(vmA, a0, q0); q1 = fmaf(vmA, a1, q1);
        P0 = fmaf(vB, bb0, P0);  P1 = fmaf(vB, bb1, P1);
        Q0 = fmaf(vmB, bb0, Q0); Q1 = fmaf(vmB, bb1, Q1);
    }
    for (; j < e; j += 2) {
        int c = colv[j]; float v = vals[j], m = g_mt0[j];
        unsigned u = *(const unsigned*)&g_xbf[c * 64 + 2 * d2];
        float a0 = bf2f_lo(u), a1 = bf2f_hi(u);
        float vm = v * m;
        p0 = fmaf(v, a0, p0);  p1 = fmaf(v, a1, p1);
        q0 = fmaf(vm, a0, q0); q1 = fmaf(vm, a1, q1);
    }
    p0 += P0; p1 += P1; q0 += Q0; q1 += Q1;
    p0 += __shfl_xor(p0, 32, 64); p1 += __shfl_xor(p1, 32, 64);
    q0 += __shfl_xor(q0, 32, 64); q1 += __shfl_xor(q1, 32, 64);
    if (el == 0) {
        uint2 pk;
        pk.x = (unsigned)f2bf(p0) | ((unsigned)f2bf(q0) << 16);
        pk.y = (unsigned)f2bf(p1) | ((unsigned)f2bf(q1) << 16);
        *(uint2*)&g_ABh[w * 128 + 4 * d2] = pk;
        *(unsigned*)&g_c1h[w * 64 + 2 * d2] =
            (unsigned)f2bf(p0) | ((unsigned)f2bf(p1) << 16);
    }
}

// ---------------------------------------------------------------------------
// L4: s2 (cur2+t2+emb_t, cur2h out) merged with nm0 (sm0 from cur1h)
// ---------------------------------------------------------------------------
__global__ __launch_bounds__(256) void s2_nm0_kernel(
    const int* __restrict__ colv, const float* __restrict__ vals,
    const float* __restrict__ x, float* __restrict__ emb_t,
    const float* __restrict__ sb1, const float* __restrict__ sW2,
    const float* __restrict__ sb2, const float* __restrict__ snz, int n)
{
    if (blockIdx.x >= 12500) {
        nm_body(blockIdx.x - 12500, g_c1h, 0, sb1, sW2, sb2, snz, g_sm0, n);
        return;
    }
    int w = (blockIdx.x * 256 + threadIdx.x) >> 6;
    int lane = threadIdx.x & 63;
    int el = lane >> 5, d2 = lane & 31;
    int s = g_rowptr[w], e = g_rowptr[w + 1];
    float c0 = 0.f, c1 = 0.f, t0 = 0.f, t1 = 0.f;
    float C0 = 0.f, C1 = 0.f, T0 = 0.f, T1 = 0.f;
    int j = s + el;
    for (; j + 2 < e; j += 4) {
        int cA = colv[j];      float vA = vals[j];     float mA = g_mt1[j];
        int cB = colv[j + 2];  float vB = vals[j + 2]; float mB = g_mt1[j + 2];
        uint2 UA = *(const uint2*)&g_ABh[cA * 128 + 4 * d2];
        uint2 UB = *(const uint2*)&g_ABh[cB * 128 + 4 * d2];
        float vmA = vA * mA, vmB = vB * mB;
        c0 = fmaf(vA, bf2f_lo(UA.x), c0); t0 = fmaf(vmA, bf2f_hi(UA.x), t0);
        c1 = fmaf(vA, bf2f_lo(UA.y), c1); t1 = fmaf(vmA, bf2f_hi(UA.y), t1);
        C0 = fmaf(vB, bf2f_lo(UB.x), C0); T0 = fmaf(vmB, bf2f_hi(UB.x), T0);
        C1 = fmaf(vB, bf2f_lo(UB.y), C1); T1 = fmaf(vmB, bf2f_hi(UB.y), T1);
    }
    for (; j < e; j += 2) {
        int c = colv[j]; float v = vals[j], m = g_mt1[j];
        uint2 U = *(const uint2*)&g_ABh[c * 128 + 4 * d2];
        float vm = v * m;
        c0 = fmaf(v, bf2f_lo(U.x), c0); t0 = fmaf(vm, bf2f_hi(U.x), t0);
        c1 = fmaf(v, bf2f_lo(U.y), c1); t1 = fmaf(vm, bf2f_hi(U.y), t1);
    }
    c0 += C0; c1 += C1; t0 += T0; t1 += T1;
    c0 += __shfl_xor(c0, 32, 64); c1 += __shfl_xor(c1, 32, 64);
    t0 += __shfl_xor(t0, 32, 64); t1 += __shfl_xor(t1, 32, 64);
    if (el == 0) {
        int o2 = w * 64 + 2 * d2;
        uint2 U2 = *(const uint2*)&g_ABh[w * 128 + 4 * d2];
        float2 et;
        et.x = (x[o2]     + bf2f_hi(U2.x) + t0) * (1.0f / 3.0f);
        et.y = (x[o2 + 1] + bf2f_hi(U2.y) + t1) * (1.0f / 3.0f);
        *(float2*)&emb_t[o2] = et;
        *(unsigned*)&g_c2h[o2] = (unsigned)f2bf(c0) | ((unsigned)f2bf(c1) << 16);
    }
}

// ---------------------------------------------------------------------------
// rwgate body (half-wave split)
// ---------------------------------------------------------------------------
__device__ __forceinline__ void rw_body(
    int bid, const int* __restrict__ rw_col, const float* __restrict__ rwv,
    const unsigned short* __restrict__ cur, const float* __restrict__ smask,
    unsigned short* __restrict__ outg)
{
    int w = (bid * 256 + threadIdx.x) >> 6;
    int lane = threadIdx.x & 63;
    int el = lane >> 5, d2 = lane & 31;
    int base = w * WKLEN;
    float a0 = 0.f, a1 = 0.f;
    for (int j = el; j < WKLEN; j += 2) {
        int c = rw_col[base + j];
        float v = rwv[base + j];
        unsigned u = *(const unsigned*)&cur[c * 64 + 2 * d2];
        a0 = fmaf(v, bf2f_lo(u), a0);
        a1 = fmaf(v, bf2f_hi(u), a1);
    }
    a0 += __shfl_xor(a0, 32, 64);
    a1 += __shfl_xor(a1, 32, 64);
    if (el == 0) {
        float sm = smask[w];
        unsigned u = *(const unsigned*)&cur[w * 64 + 2 * d2];
        float r0 = sm * bf2f_lo(u) + (1.f - sm) * a0;
        float r1 = sm * bf2f_hi(u) + (1.f - sm) * a1;
        *(unsigned*)&outg[w * 64 + 2 * d2] =
            (unsigned)f2bf(r0) | ((unsigned)f2bf(r1) << 16);
    }
}

// ---------------------------------------------------------------------------
// L5: rwgate(x->g0) merged with nm1 (sm1 from cur2h)
// ---------------------------------------------------------------------------
__global__ __launch_bounds__(256) void rw0_nm1_kernel(
    const int* __restrict__ rw_col, const float* __restrict__ rwv,
    const float* __restrict__ sb1, const float* __restrict__ sW2,
    const float* __restrict__ sb2, const float* __restrict__ snz, int n)
{
    if (blockIdx.x >= 12500) {
        nm_body(blockIdx.x - 12500, g_c2h, 1, sb1, sW2, sb2, snz, g_sm1, n);
        return;
    }
    rw_body(blockIdx.x, rw_col, rwv, g_xbf, g_sm0, g_g0h);
}

// ---------------------------------------------------------------------------
// L6: c1 = spmm(vals, g0)
// ---------------------------------------------------------------------------
__global__ __launch_bounds__(256) void spmm10_kernel(
    const int* __restrict__ colv, const float* __restrict__ vals, int n)
{
    int w = (blockIdx.x * 256 + threadIdx.x) >> 6;
    int lane = threadIdx.x & 63;
    int el = lane >> 5, d2 = lane & 31;
    int s = g_rowptr[w], e = g_rowptr[w + 1];
    float a0 = 0.f, a1 = 0.f, A0 = 0.f, A1 = 0.f;
    int j = s + el;
    for (; j + 2 < e; j += 4) {
        int cA = colv[j];     float vA = vals[j];
        int cB = colv[j + 2]; float vB = vals[j + 2];
        unsigned uA = *(const unsigned*)&g_g0h[cA * 64 + 2 * d2];
        unsigned uB = *(const unsigned*)&g_g0h[cB * 64 + 2 * d2];
        a0 = fmaf(vA, bf2f_lo(uA), a0); a1 = fmaf(vA, bf2f_hi(uA), a1);
        A0 = fmaf(vB, bf2f_lo(uB), A0); A1 = fmaf(vB, bf2f_hi(uB), A1);
    }
    for (; j < e; j += 2) {
        int c = colv[j]; float v = vals[j];
        unsigned u = *(const unsigned*)&g_g0h[c * 64 + 2 * d2];
        a0 = fmaf(v, bf2f_lo(u), a0); a1 = fmaf(v, bf2f_hi(u), a1);
    }
    a0 += A0; a1 += A1;
    a0 += __shfl_xor(a0, 32, 64); a1 += __shfl_xor(a1, 32, 64);
    if (el == 0)
        *(unsigned*)&g_sc1h[w * 64 + 2 * d2] =
            (unsigned)f2bf(a0) | ((unsigned)f2bf(a1) << 16);
}

// ---------------------------------------------------------------------------
// L7: g1 = rwgate(c1)
// ---------------------------------------------------------------------------
__global__ __launch_bounds__(256) void rw1_kernel(
    const int* __restrict__ rw_col, const float* __restrict__ rwv)
{
    rw_body(blockIdx.x, rw_col, rwv, g_sc1h, g_sm1, g_g0h);
}

// ---------------------------------------------------------------------------
// L8: emb_s = (x + c1 + spmm(vals, g1))/3, merged with finalize
// ---------------------------------------------------------------------------
__global__ __launch_bounds__(256) void spmm12_fin_kernel(
    const int* __restrict__ colv, const float* __restrict__ vals,
    const float* __restrict__ x, float* __restrict__ emb_s,
    float* __restrict__ out, int n)
{
    if (blockIdx.x >= 12500) {
        __shared__ float red[256];
        float s = 0.f;
        for (int i = threadIdx.x; i < n; i += 256) s += g_sm0[i] + g_sm1[i];
        red[threadIdx.x] = s;
        __syncthreads();
        for (int off = 128; off >= 1; off >>= 1) {
            if (threadIdx.x < off) red[threadIdx.x] += red[threadIdx.x + off];
            __syncthreads();
        }
        if (threadIdx.x == 0) {
            out[6400000] = 0.0f;
            out[6400001] = red[0] / (2.0f * n);
        }
        return;
    }
    int w = (blockIdx.x * 256 + threadIdx.x) >> 6;
    int lane = threadIdx.x & 63;
    int el = lane >> 5, d2 = lane & 31;
    int s = g_rowptr[w], e = g_rowptr[w + 1];
    float a0 = 0.f, a1 = 0.f, A0 = 0.f, A1 = 0.f;
    int j = s + el;
    for (; j + 2 < e; j += 4) {
        int cA = colv[j];     float vA = vals[j];
        int cB = colv[j + 2]; float vB = vals[j + 2];
        unsigned uA = *(const unsigned*)&g_g0h[cA * 64 + 2 * d2];
        unsigned uB = *(const unsigned*)&g_g0h[cB * 64 + 2 * d2];
        a0 = fmaf(vA, bf2f_lo(uA), a0); a1 = fmaf(vA, bf2f_hi(uA), a1);
        A0 = fmaf(vB, bf2f_lo(uB), A0); A1 = fmaf(vB, bf2f_hi(uB), A1);
    }
    for (; j < e; j += 2) {
        int c = colv[j]; float v = vals[j];
        unsigned u = *(const unsigned*)&g_g0h[c * 64 + 2 * d2];
        a0 = fmaf(v, bf2f_lo(u), a0); a1 = fmaf(v, bf2f_hi(u), a1);
    }
    a0 += A0; a1 += A1;
    a0 += __shfl_xor(a0, 32, 64); a1 += __shfl_xor(a1, 32, 64);
    if (el == 0) {
        int o2 = w * 64 + 2 * d2;
        unsigned uc = *(const unsigned*)&g_sc1h[o2];
        float2 es;
        es.x = (x[o2]     + bf2f_lo(uc) + a0) * (1.0f / 3.0f);
        es.y = (x[o2 + 1] + bf2f_hi(uc) + a1) * (1.0f / 3.0f);
        *(float2*)&emb_s[o2] = es;
    }
}

extern "C" void kernel_launch(void* const* d_in, const int* in_sizes, int n_in,
                              void* d_out, int out_size, void* d_ws, size_t ws_size,
                              hipStream_t stream)
{
    const float* x    = (const float*)d_in[0];
    const float* vals = (const float*)d_in[1];
    const float* rwv  = (const float*)d_in[2];
    const float* tW1  = (const float*)d_in[3];
    const float* tb1  = (const float*)d_in[4];
    const float* tW2  = (const float*)d_in[5];
    const float* tb2  = (const float*)d_in[6];
    const float* sW1  = (const float*)d_in[7];
    const float* sb1  = (const float*)d_in[8];
    const float* sW2  = (const float*)d_in[9];
    const float* sb2  = (const float*)d_in[10];
    const float* tnz  = (const float*)d_in[11];
    const float* snz  = (const float*)d_in[12];
    const int* row   = (const int*)d_in[13];
    const int* colv  = (const int*)d_in[14];
    const int* rwcol = (const int*)d_in[16];

    const int n = NNODES;
    const int nE = in_sizes[1];

    float* out   = (float*)d_out;
    float* emb_t = out;
    float* emb_s = out + 3200000;
    float* masko = out + 6400002;

    // L1: misc prep
    misc_kernel<<<1771, 256, 0, stream>>>(x, tW1, sW1, row, n, nE);
    // L2a: P = X @ W1_halves (4 sets)
    prep2_kernel<<<782, 256, 0, stream>>>(n);
    // L2b: edge masks
    edge_mask_kernel<<<nE / 32, 256, 0, stream>>>(tb1, tW2, tb2, tnz,
                                                  row, colv, masko, nE);
    // L3: s1 (cur1|t1 packed + cur1h)
    s1_kernel<<<12500, 256, 0, stream>>>(colv, vals, n);
    // L4: s2 (emb_t, cur2h) + nm0 (sm0)
    s2_nm0_kernel<<<12500 + 782, 256, 0, stream>>>(colv, vals, x, emb_t,
                                                   sb1, sW2, sb2, snz, n);
    // L5: rwgate(x->g0) + nm1 (sm1)
    rw0_nm1_kernel<<<12500 + 782, 256, 0, stream>>>(rwcol, rwv,
                                                    sb1 + 64, sW2 + 64, sb2 + 1,
                                                    snz + n, n);
    // L6: c1 = spmm(vals, g0)
    spmm10_kernel<<<12500, 256, 0, stream>>>(colv, vals, n);
    // L7: g1 = rwgate(c1)
    rw1_kernel<<<12500, 256, 0, stream>>>(rwcol, rwv);
    // L8: emb_s + scalars
    spmm12_fin_kernel<<<12501, 256, 0, stream>>>(colv, vals, x, emb_s, out, n);
}

// Round 9
// 352.860 us; speedup vs baseline: 2.0032x; 1.1578x over previous
//
#include <hip/hip_runtime.h>

#define NNODES 50000
#define EDIM 64
#define WKLEN 9
#define NEDGE 800000
#define NPAD (NNODES + 64)

using bf16x8 = __attribute__((ext_vector_type(8))) __bf16;
using f32x4  = __attribute__((ext_vector_type(4))) float;

// ---- static device scratch ----
__device__ __align__(256) unsigned short g_xbf[NPAD * EDIM];     // bf16 x (padded)
__device__ __align__(256) unsigned short g_ABh[NNODES * 128];    // packed (cur1,t1)
__device__ __align__(256) unsigned short g_c1h[NPAD * EDIM];     // cur1 bf16 (nm0)
__device__ __align__(256) unsigned short g_c2h[NPAD * EDIM];     // cur2 bf16 (nm1)
__device__ __align__(256) unsigned short g_g0h[NNODES * EDIM];   // g0 then g1
__device__ __align__(256) unsigned short g_sc1h[NNODES * EDIM];  // s-branch c1
__device__ __align__(256) unsigned short g_Pr[NNODES * 128];     // x@W1top L0|L1
__device__ __align__(256) unsigned short g_Pc[NNODES * 128];     // x@W1bot L0|L1
__device__ __align__(256) float g_mt0[NEDGE];
__device__ __align__(256) float g_mt1[NEDGE];
__device__ __align__(256) float g_sm0[NNODES];
__device__ __align__(256) float g_sm1[NNODES];
__device__ __align__(256) int   g_rowptr[NNODES + 1];
__device__ __align__(256) unsigned short g_Tswz[2048 * 8];  // edge W1-half frags
__device__ __align__(256) unsigned short g_Sswz[1024 * 8];  // node-MLP W1 frags

__device__ __forceinline__ unsigned short f2bf(float f) {
    union { float f; unsigned int i; } v;
    v.f = f;
    unsigned int r = v.i + 0x7FFFu + ((v.i >> 16) & 1u);
    return (unsigned short)(r >> 16);
}
__device__ __forceinline__ float bf2f_lo(unsigned int u) {
    union { unsigned int i; float f; } v; v.i = u << 16; return v.f;
}
__device__ __forceinline__ float bf2f_hi(unsigned int u) {
    union { unsigned int i; float f; } v; v.i = u & 0xFFFF0000u; return v.f;
}

// ---------------------------------------------------------------------------
// L1: misc — x->bf16 | rowptr | W1-half swizzle (edge) | W1 swizzle (node)
// ---------------------------------------------------------------------------
__global__ __launch_bounds__(256) void misc_kernel(
    const float* __restrict__ x, const float* __restrict__ tW1,
    const float* __restrict__ sW1, const int* __restrict__ row,
    int n, int nE)
{
    int bid = blockIdx.x, tid = threadIdx.x;
    if (bid < 1563) {
        int i = bid * 256 + tid;
        if (i < NNODES * EDIM / 8) {
            const float* src = x + i * 8;
            union { unsigned short s[8]; uint4 q; } u;
#pragma unroll
            for (int j = 0; j < 8; ++j) u.s[j] = f2bf(src[j]);
            *(uint4*)&g_xbf[i * 8] = u.q;
        }
    } else if (bid < 1759) {
        int i = (bid - 1563) * 256 + tid;
        if (i > n) return;
        int lo = 0, hi = nE;
        while (lo < hi) {
            int mid = (lo + hi) >> 1;
            if (row[mid] < i) lo = mid + 1; else hi = mid;
        }
        g_rowptr[i] = lo;
    } else if (bid < 1767) {
        int t = (bid - 1759) * 256 + tid;   // 0..2047
        int s = t >> 9, f = (t >> 6) & 7, ln = t & 63;
        int li = s >> 1, half = s & 1, ks = f >> 2, nn = f & 3;
        int q = ln >> 4, mcl = ln & 15;
        union { unsigned short sv[8]; uint4 q4; } u;
#pragma unroll
        for (int j = 0; j < 8; ++j) {
            int kg = half * 64 + ks * 32 + q * 8 + j;
            u.sv[j] = f2bf(tW1[li * 8192 + kg * 64 + nn * 16 + mcl]);
        }
        *(uint4*)&g_Tswz[t * 8] = u.q4;
    } else {
        int t = (bid - 1767) * 256 + tid;  // 0..1023
        int li = t >> 9, ks = (t >> 8) & 1, nn = (t >> 6) & 3, ln = t & 63;
        int q = ln >> 4, mcl = ln & 15;
        union { unsigned short sv[8]; uint4 q4; } u;
#pragma unroll
        for (int j = 0; j < 8; ++j)
            u.sv[j] = f2bf(sW1[li * 4096 + (ks * 32 + q * 8 + j) * 64 + nn * 16 + mcl]);
        *(uint4*)&g_Sswz[t * 8] = u.q4;
    }
}

// ---------------------------------------------------------------------------
// L2a: prep2 — P = X @ W1_half for 4 sets via MFMA, bf16 packed out.
// ---------------------------------------------------------------------------
__global__ __launch_bounds__(256) void prep2_kernel(int n)
{
    int tid = threadIdx.x;
    int wave = tid >> 6, lane = tid & 63;
    int mc = lane & 15, quad = lane >> 4;
    int nb = blockIdx.x * 64 + wave * 16;
    const unsigned short* bp = g_xbf + (nb + mc) * 64 + quad * 8;
    bf16x8 af0 = *(const bf16x8*)bp;
    bf16x8 af1 = *(const bf16x8*)(bp + 32);
    const f32x4 zero = {0.f, 0.f, 0.f, 0.f};
#pragma unroll
    for (int s = 0; s < 4; ++s) {
        int li = s >> 1, half = s & 1;
        f32x4 acc[4];
#pragma unroll
        for (int nn = 0; nn < 4; ++nn) acc[nn] = zero;
#pragma unroll
        for (int nn = 0; nn < 4; ++nn) {
            bf16x8 b0 = *(const bf16x8*)&g_Tswz[((s * 8 + nn) * 64 + lane) * 8];
            bf16x8 b1 = *(const bf16x8*)&g_Tswz[((s * 8 + 4 + nn) * 64 + lane) * 8];
            acc[nn] = __builtin_amdgcn_mfma_f32_16x16x32_bf16(af0, b0, acc[nn], 0, 0, 0);
            acc[nn] = __builtin_amdgcn_mfma_f32_16x16x32_bf16(af1, b1, acc[nn], 0, 0, 0);
        }
        unsigned short* dst = half ? g_Pc : g_Pr;
#pragma unroll
        for (int nn = 0; nn < 4; ++nn)
#pragma unroll
            for (int r = 0; r < 4; ++r) {
                int node = nb + quad * 4 + r;
                if (node < n)
                    dst[node * 128 + li * 64 + nn * 16 + mc] = f2bf(acc[nn][r]);
            }
    }
}

// ---------------------------------------------------------------------------
// L2b: edge masks — wave = 8 edges x 8 lanes x 8 dims; no MFMA, no LDS.
// ---------------------------------------------------------------------------
__global__ __launch_bounds__(256) void edge_mask_kernel(
    const float* __restrict__ tb1, const float* __restrict__ tW2,
    const float* __restrict__ tb2, const float* __restrict__ tnoise,
    const int* __restrict__ row, const int* __restrict__ col,
    float* __restrict__ mask_out, int nE)
{
    int tid = threadIdx.x;
    int lane = tid & 63;
    int sub = lane & 7;
    int eg = lane >> 3;
    int wv = (blockIdx.x * 256 + tid) >> 6;
    int e = wv * 8 + eg;

    float b1_0[8], b1_1[8], w2_0[8], w2_1[8];
    *(float4*)&b1_0[0] = *(const float4*)&tb1[sub * 8];
    *(float4*)&b1_0[4] = *(const float4*)&tb1[sub * 8 + 4];
    *(float4*)&b1_1[0] = *(const float4*)&tb1[64 + sub * 8];
    *(float4*)&b1_1[4] = *(const float4*)&tb1[64 + sub * 8 + 4];
    *(float4*)&w2_0[0] = *(const float4*)&tW2[sub * 8];
    *(float4*)&w2_0[4] = *(const float4*)&tW2[sub * 8 + 4];
    *(float4*)&w2_1[0] = *(const float4*)&tW2[64 + sub * 8];
    *(float4*)&w2_1[4] = *(const float4*)&tW2[64 + sub * 8 + 4];

    int rn = row[e], cn = col[e];
    uint4 qr0 = *(const uint4*)&g_Pr[rn * 128 + sub * 8];
    uint4 qr1 = *(const uint4*)&g_Pr[rn * 128 + 64 + sub * 8];
    uint4 qc0 = *(const uint4*)&g_Pc[cn * 128 + sub * 8];
    uint4 qc1 = *(const uint4*)&g_Pc[cn * 128 + 64 + sub * 8];

    float p0 = 0.f, p1 = 0.f;
    unsigned r0[4] = {qr0.x, qr0.y, qr0.z, qr0.w};
    unsigned r1[4] = {qr1.x, qr1.y, qr1.z, qr1.w};
    unsigned c0[4] = {qc0.x, qc0.y, qc0.z, qc0.w};
    unsigned c1[4] = {qc1.x, qc1.y, qc1.z, qc1.w};
#pragma unroll
    for (int k = 0; k < 4; ++k) {
        float hA = fmaxf(bf2f_lo(r0[k]) + bf2f_lo(c0[k]) + b1_0[2 * k], 0.f);
        float hB = fmaxf(bf2f_hi(r0[k]) + bf2f_hi(c0[k]) + b1_0[2 * k + 1], 0.f);
        p0 = fmaf(hA, w2_0[2 * k], p0);
        p0 = fmaf(hB, w2_0[2 * k + 1], p0);
        float gA = fmaxf(bf2f_lo(r1[k]) + bf2f_lo(c1[k]) + b1_1[2 * k], 0.f);
        float gB = fmaxf(bf2f_hi(r1[k]) + bf2f_hi(c1[k]) + b1_1[2 * k + 1], 0.f);
        p1 = fmaf(gA, w2_1[2 * k], p1);
        p1 = fmaf(gB, w2_1[2 * k + 1], p1);
    }
#pragma unroll
    for (int off = 1; off <= 4; off <<= 1) {
        p0 += __shfl_xor(p0, off, 64);
        p1 += __shfl_xor(p1, off, 64);
    }
    if (sub == 0) {
        float z0 = (tnoise[e] + p0 + tb2[0]) * 2.0f;
        float m0 = 1.0f / (1.0f + expf(-z0));
        g_mt0[e] = m0;
        float z1 = (tnoise[nE + e] + p1 + tb2[1]) * 2.0f;
        float m1 = 1.0f / (1.0f + expf(-z1));
        g_mt1[e] = m1;
        mask_out[e] = m1;
    }
}

// ---------------------------------------------------------------------------
// node-MLP via MFMA: 16 nodes/wave
// ---------------------------------------------------------------------------
__device__ __forceinline__ void nm_body(
    int bid, const unsigned short* __restrict__ cur, int li,
    const float* __restrict__ b1, const float* __restrict__ W2,
    const float* __restrict__ b2, const float* __restrict__ noise,
    float* __restrict__ smout, int n)
{
    int tid = threadIdx.x;
    int wave = tid >> 6, lane = tid & 63;
    int mc = lane & 15, quad = lane >> 4;
    int nb = bid * 64 + wave * 16;
    const unsigned short* basep = cur + (nb + mc) * 64 + quad * 8;
    bf16x8 af0 = *(const bf16x8*)basep;
    bf16x8 af1 = *(const bf16x8*)(basep + 32);
    f32x4 acc[4];
    const f32x4 zero = {0.f, 0.f, 0.f, 0.f};
#pragma unroll
    for (int nn = 0; nn < 4; ++nn) acc[nn] = zero;
#pragma unroll
    for (int nn = 0; nn < 4; ++nn) {
        bf16x8 b0 = *(const bf16x8*)&g_Sswz[((li * 8 + nn) * 64 + lane) * 8];
        bf16x8 b1f = *(const bf16x8*)&g_Sswz[((li * 8 + 4 + nn) * 64 + lane) * 8];
        acc[nn] = __builtin_amdgcn_mfma_f32_16x16x32_bf16(af0, b0, acc[nn], 0, 0, 0);
        acc[nn] = __builtin_amdgcn_mfma_f32_16x16x32_bf16(af1, b1f, acc[nn], 0, 0, 0);
    }
    float p[4];
#pragma unroll
    for (int r = 0; r < 4; ++r) {
        float s = 0.f;
#pragma unroll
        for (int nn = 0; nn < 4; ++nn) {
            float h = acc[nn][r] + b1[nn * 16 + mc];
            s = fmaf(fmaxf(h, 0.f), W2[nn * 16 + mc], s);
        }
        p[r] = s;
    }
#pragma unroll
    for (int off = 8; off >= 1; off >>= 1)
#pragma unroll
        for (int r = 0; r < 4; ++r) p[r] += __shfl_xor(p[r], off, 64);
    if (mc == 0) {
        float b2v = b2[0];
#pragma unroll
        for (int r = 0; r < 4; ++r) {
            int node = nb + quad * 4 + r;
            if (node < n) {
                float z = (noise[node] + p[r] + b2v) * 2.0f;
                smout[node] = 1.0f / (1.0f + expf(-z));
            }
        }
    }
}

// ---------------------------------------------------------------------------
// L3: s1 — row per 32-lane half, 4 gather chains, no shuffles.
// ---------------------------------------------------------------------------
__global__ __launch_bounds__(256) void s1_kernel(
    const int* __restrict__ colv, const float* __restrict__ vals, int n)
{
    int w = blockIdx.x * 8 + (threadIdx.x >> 5);
    int d2 = threadIdx.x & 31;
    int s = g_rowptr[w], e = g_rowptr[w + 1];
    float pl[4] = {0.f, 0.f, 0.f, 0.f}, ph[4] = {0.f, 0.f, 0.f, 0.f};
    float ql[4] = {0.f, 0.f, 0.f, 0.f}, qh[4] = {0.f, 0.f, 0.f, 0.f};
    int j = s;
    for (; j + 3 < e; j += 4) {
        int c0 = colv[j], c1 = colv[j + 1], c2 = colv[j + 2], c3 = colv[j + 3];
        unsigned u0 = *(const unsigned*)&g_xbf[c0 * 64 + 2 * d2];
        unsigned u1 = *(const unsigned*)&g_xbf[c1 * 64 + 2 * d2];
        unsigned u2 = *(const unsigned*)&g_xbf[c2 * 64 + 2 * d2];
        unsigned u3 = *(const unsigned*)&g_xbf[c3 * 64 + 2 * d2];
        float v0 = vals[j], v1 = vals[j + 1], v2 = vals[j + 2], v3 = vals[j + 3];
        float m0 = g_mt0[j], m1 = g_mt0[j + 1], m2 = g_mt0[j + 2], m3 = g_mt0[j + 3];
        float vm0 = v0 * m0, vm1 = v1 * m1, vm2 = v2 * m2, vm3 = v3 * m3;
        pl[0] = fmaf(v0, bf2f_lo(u0), pl[0]); ph[0] = fmaf(v0, bf2f_hi(u0), ph[0]);
        ql[0] = fmaf(vm0, bf2f_lo(u0), ql[0]); qh[0] = fmaf(vm0, bf2f_hi(u0), qh[0]);
        pl[1] = fmaf(v1, bf2f_lo(u1), pl[1]); ph[1] = fmaf(v1, bf2f_hi(u1), ph[1]);
        ql[1] = fmaf(vm1, bf2f_lo(u1), ql[1]); qh[1] = fmaf(vm1, bf2f_hi(u1), qh[1]);
        pl[2] = fmaf(v2, bf2f_lo(u2), pl[2]); ph[2] = fmaf(v2, bf2f_hi(u2), ph[2]);
        ql[2] = fmaf(vm2, bf2f_lo(u2), ql[2]); qh[2] = fmaf(vm2, bf2f_hi(u2), qh[2]);
        pl[3] = fmaf(v3, bf2f_lo(u3), pl[3]); ph[3] = fmaf(v3, bf2f_hi(u3), ph[3]);
        ql[3] = fmaf(vm3, bf2f_lo(u3), ql[3]); qh[3] = fmaf(vm3, bf2f_hi(u3), qh[3]);
    }
    for (; j < e; ++j) {
        int c = colv[j]; float v = vals[j], m = g_mt0[j];
        unsigned u = *(const unsigned*)&g_xbf[c * 64 + 2 * d2];
        float vm = v * m;
        pl[0] = fmaf(v, bf2f_lo(u), pl[0]); ph[0] = fmaf(v, bf2f_hi(u), ph[0]);
        ql[0] = fmaf(vm, bf2f_lo(u), ql[0]); qh[0] = fmaf(vm, bf2f_hi(u), qh[0]);
    }
    float p0 = (pl[0] + pl[1]) + (pl[2] + pl[3]);
    float p1 = (ph[0] + ph[1]) + (ph[2] + ph[3]);
    float q0 = (ql[0] + ql[1]) + (ql[2] + ql[3]);
    float q1 = (qh[0] + qh[1]) + (qh[2] + qh[3]);
    uint2 pk;
    pk.x = (unsigned)f2bf(p0) | ((unsigned)f2bf(q0) << 16);
    pk.y = (unsigned)f2bf(p1) | ((unsigned)f2bf(q1) << 16);
    *(uint2*)&g_ABh[w * 128 + 4 * d2] = pk;
    *(unsigned*)&g_c1h[w * 64 + 2 * d2] =
        (unsigned)f2bf(p0) | ((unsigned)f2bf(p1) << 16);
}

// ---------------------------------------------------------------------------
// L4: s2 (row-per-half, 4 chains) merged with nm0
// ---------------------------------------------------------------------------
__global__ __launch_bounds__(256) void s2_nm0_kernel(
    const int* __restrict__ colv, const float* __restrict__ vals,
    const float* __restrict__ x, float* __restrict__ emb_t,
    const float* __restrict__ sb1, const float* __restrict__ sW2,
    const float* __restrict__ sb2, const float* __restrict__ snz, int n)
{
    if (blockIdx.x >= 6250) {
        nm_body(blockIdx.x - 6250, g_c1h, 0, sb1, sW2, sb2, snz, g_sm0, n);
        return;
    }
    int w = blockIdx.x * 8 + (threadIdx.x >> 5);
    int d2 = threadIdx.x & 31;
    int s = g_rowptr[w], e = g_rowptr[w + 1];
    float cl[4] = {0.f, 0.f, 0.f, 0.f}, ch[4] = {0.f, 0.f, 0.f, 0.f};
    float tl[4] = {0.f, 0.f, 0.f, 0.f}, th[4] = {0.f, 0.f, 0.f, 0.f};
    int j = s;
    for (; j + 3 < e; j += 4) {
        int c0 = colv[j], c1 = colv[j + 1], c2 = colv[j + 2], c3 = colv[j + 3];
        uint2 U0 = *(const uint2*)&g_ABh[c0 * 128 + 4 * d2];
        uint2 U1 = *(const uint2*)&g_ABh[c1 * 128 + 4 * d2];
        uint2 U2 = *(const uint2*)&g_ABh[c2 * 128 + 4 * d2];
        uint2 U3 = *(const uint2*)&g_ABh[c3 * 128 + 4 * d2];
        float v0 = vals[j], v1 = vals[j + 1], v2 = vals[j + 2], v3 = vals[j + 3];
        float m0 = g_mt1[j], m1 = g_mt1[j + 1], m2 = g_mt1[j + 2], m3 = g_mt1[j + 3];
        float vm0 = v0 * m0, vm1 = v1 * m1, vm2 = v2 * m2, vm3 = v3 * m3;
        cl[0] = fmaf(v0, bf2f_lo(U0.x), cl[0]); tl[0] = fmaf(vm0, bf2f_hi(U0.x), tl[0]);
        ch[0] = fmaf(v0, bf2f_lo(U0.y), ch[0]); th[0] = fmaf(vm0, bf2f_hi(U0.y), th[0]);
        cl[1] = fmaf(v1, bf2f_lo(U1.x), cl[1]); tl[1] = fmaf(vm1, bf2f_hi(U1.x), tl[1]);
        ch[1] = fmaf(v1, bf2f_lo(U1.y), ch[1]); th[1] = fmaf(vm1, bf2f_hi(U1.y), th[1]);
        cl[2] = fmaf(v2, bf2f_lo(U2.x), cl[2]); tl[2] = fmaf(vm2, bf2f_hi(U2.x), tl[2]);
        ch[2] = fmaf(v2, bf2f_lo(U2.y), ch[2]); th[2] = fmaf(vm2, bf2f_hi(U2.y), th[2]);
        cl[3] = fmaf(v3, bf2f_lo(U3.x), cl[3]); tl[3] = fmaf(vm3, bf2f_hi(U3.x), tl[3]);
        ch[3] = fmaf(v3, bf2f_lo(U3.y), ch[3]); th[3] = fmaf(vm3, bf2f_hi(U3.y), th[3]);
    }
    for (; j < e; ++j) {
        int c = colv[j]; float v = vals[j], m = g_mt1[j];
        uint2 U = *(const uint2*)&g_ABh[c * 128 + 4 * d2];
        float vm = v * m;
        cl[0] = fmaf(v, bf2f_lo(U.x), cl[0]); tl[0] = fmaf(vm, bf2f_hi(U.x), tl[0]);
        ch[0] = fmaf(v, bf2f_lo(U.y), ch[0]); th[0] = fmaf(vm, bf2f_hi(U.y), th[0]);
    }
    float c0s = (cl[0] + cl[1]) + (cl[2] + cl[3]);
    float c1s = (ch[0] + ch[1]) + (ch[2] + ch[3]);
    float t0s = (tl[0] + tl[1]) + (tl[2] + tl[3]);
    float t1s = (th[0] + th[1]) + (th[2] + th[3]);
    int o2 = w * 64 + 2 * d2;
    uint2 U2v = *(const uint2*)&g_ABh[w * 128 + 4 * d2];
    float2 et;
    et.x = (x[o2]     + bf2f_hi(U2v.x) + t0s) * (1.0f / 3.0f);
    et.y = (x[o2 + 1] + bf2f_hi(U2v.y) + t1s) * (1.0f / 3.0f);
    *(float2*)&emb_t[o2] = et;
    *(unsigned*)&g_c2h[o2] = (unsigned)f2bf(c0s) | ((unsigned)f2bf(c1s) << 16);
}

// ---------------------------------------------------------------------------
// rwgate body: row per half, fully unrolled 9 gather chains
// ---------------------------------------------------------------------------
__device__ __forceinline__ void rw_body(
    int bid, const int* __restrict__ rw_col, const float* __restrict__ rwv,
    const unsigned short* __restrict__ cur, const float* __restrict__ smask,
    unsigned short* __restrict__ outg)
{
    int w = bid * 8 + (threadIdx.x >> 5);
    int d2 = threadIdx.x & 31;
    int base = w * WKLEN;
    float a0 = 0.f, a1 = 0.f;
#pragma unroll
    for (int j = 0; j < WKLEN; ++j) {
        int c = rw_col[base + j];
        float v = rwv[base + j];
        unsigned u = *(const unsigned*)&cur[c * 64 + 2 * d2];
        a0 = fmaf(v, bf2f_lo(u), a0);
        a1 = fmaf(v, bf2f_hi(u), a1);
    }
    float sm = smask[w];
    unsigned u = *(const unsigned*)&cur[w * 64 + 2 * d2];
    float r0 = sm * bf2f_lo(u) + (1.f - sm) * a0;
    float r1 = sm * bf2f_hi(u) + (1.f - sm) * a1;
    *(unsigned*)&outg[w * 64 + 2 * d2] =
        (unsigned)f2bf(r0) | ((unsigned)f2bf(r1) << 16);
}

// ---------------------------------------------------------------------------
// L5: rwgate(x->g0) merged with nm1 (sm1 from cur2h)
// ---------------------------------------------------------------------------
__global__ __launch_bounds__(256) void rw0_nm1_kernel(
    const int* __restrict__ rw_col, const float* __restrict__ rwv,
    const float* __restrict__ sb1, const float* __restrict__ sW2,
    const float* __restrict__ sb2, const float* __restrict__ snz, int n)
{
    if (blockIdx.x >= 6250) {
        nm_body(blockIdx.x - 6250, g_c2h, 1, sb1, sW2, sb2, snz, g_sm1, n);
        return;
    }
    rw_body(blockIdx.x, rw_col, rwv, g_xbf, g_sm0, g_g0h);
}

// ---------------------------------------------------------------------------
// L6: c1 = spmm(vals, g0) — row per half, 4 chains
// ---------------------------------------------------------------------------
__device__ __forceinline__ void spmm_body(
    int bid, const int* __restrict__ colv, const float* __restrict__ vals,
    const unsigned short* __restrict__ h, float* __restrict__ l0,
    float* __restrict__ l1, int* __restrict__ wout, int* __restrict__ d2out)
{
    int w = bid * 8 + (threadIdx.x >> 5);
    int d2 = threadIdx.x & 31;
    int s = g_rowptr[w], e = g_rowptr[w + 1];
    float al[4] = {0.f, 0.f, 0.f, 0.f}, ah[4] = {0.f, 0.f, 0.f, 0.f};
    int j = s;
    for (; j + 3 < e; j += 4) {
        int c0 = colv[j], c1 = colv[j + 1], c2 = colv[j + 2], c3 = colv[j + 3];
        unsigned u0 = *(const unsigned*)&h[c0 * 64 + 2 * d2];
        unsigned u1 = *(const unsigned*)&h[c1 * 64 + 2 * d2];
        unsigned u2 = *(const unsigned*)&h[c2 * 64 + 2 * d2];
        unsigned u3 = *(const unsigned*)&h[c3 * 64 + 2 * d2];
        float v0 = vals[j], v1 = vals[j + 1], v2 = vals[j + 2], v3 = vals[j + 3];
        al[0] = fmaf(v0, bf2f_lo(u0), al[0]); ah[0] = fmaf(v0, bf2f_hi(u0), ah[0]);
        al[1] = fmaf(v1, bf2f_lo(u1), al[1]); ah[1] = fmaf(v1, bf2f_hi(u1), ah[1]);
        al[2] = fmaf(v2, bf2f_lo(u2), al[2]); ah[2] = fmaf(v2, bf2f_hi(u2), ah[2]);
        al[3] = fmaf(v3, bf2f_lo(u3), al[3]); ah[3] = fmaf(v3, bf2f_hi(u3), ah[3]);
    }
    for (; j < e; ++j) {
        int c = colv[j]; float v = vals[j];
        unsigned u = *(const unsigned*)&h[c * 64 + 2 * d2];
        al[0] = fmaf(v, bf2f_lo(u), al[0]); ah[0] = fmaf(v, bf2f_hi(u), ah[0]);
    }
    *l0 = (al[0] + al[1]) + (al[2] + al[3]);
    *l1 = (ah[0] + ah[1]) + (ah[2] + ah[3]);
    *wout = w; *d2out = d2;
}

__global__ __launch_bounds__(256) void spmm10_kernel(
    const int* __restrict__ colv, const float* __restrict__ vals, int n)
{
    float a0, a1; int w, d2;
    spmm_body(blockIdx.x, colv, vals, g_g0h, &a0, &a1, &w, &d2);
    *(unsigned*)&g_sc1h[w * 64 + 2 * d2] =
        (unsigned)f2bf(a0) | ((unsigned)f2bf(a1) << 16);
}

// ---------------------------------------------------------------------------
// L7: g1 = rwgate(c1)
// ---------------------------------------------------------------------------
__global__ __launch_bounds__(256) void rw1_kernel(
    const int* __restrict__ rw_col, const float* __restrict__ rwv)
{
    rw_body(blockIdx.x, rw_col, rwv, g_sc1h, g_sm1, g_g0h);
}

// ---------------------------------------------------------------------------
// L8: emb_s = (x + c1 + spmm(vals, g1))/3, merged with finalize
// ---------------------------------------------------------------------------
__global__ __launch_bounds__(256) void spmm12_fin_kernel(
    const int* __restrict__ colv, const float* __restrict__ vals,
    const float* __restrict__ x, float* __restrict__ emb_s,
    float* __restrict__ out, int n)
{
    if (blockIdx.x >= 6250) {
        __shared__ float red[256];
        float s = 0.f;
        for (int i = threadIdx.x; i < n; i += 256) s += g_sm0[i] + g_sm1[i];
        red[threadIdx.x] = s;
        __syncthreads();
        for (int off = 128; off >= 1; off >>= 1) {
            if (threadIdx.x < off) red[threadIdx.x] += red[threadIdx.x + off];
            __syncthreads();
        }
        if (threadIdx.x == 0) {
            out[6400000] = 0.0f;
            out[6400001] = red[0] / (2.0f * n);
        }
        return;
    }
    float a0, a1; int w, d2;
    spmm_body(blockIdx.x, colv, vals, g_g0h, &a0, &a1, &w, &d2);
    int o2 = w * 64 + 2 * d2;
    unsigned uc = *(const unsigned*)&g_sc1h[o2];
    float2 es;
    es.x = (x[o2]     + bf2f_lo(uc) + a0) * (1.0f / 3.0f);
    es.y = (x[o2 + 1] + bf2f_hi(uc) + a1) * (1.0f / 3.0f);
    *(float2*)&emb_s[o2] = es;
}

extern "C" void kernel_launch(void* const* d_in, const int* in_sizes, int n_in,
                              void* d_out, int out_size, void* d_ws, size_t ws_size,
                              hipStream_t stream)
{
    const float* x    = (const float*)d_in[0];
    const float* vals = (const float*)d_in[1];
    const float* rwv  = (const float*)d_in[2];
    const float* tW1  = (const float*)d_in[3];
    const float* tb1  = (const float*)d_in[4];
    const float* tW2  = (const float*)d_in[5];
    const float* tb2  = (const float*)d_in[6];
    const float* sW1  = (const float*)d_in[7];
    const float* sb1  = (const float*)d_in[8];
    const float* sW2  = (const float*)d_in[9];
    const float* sb2  = (const float*)d_in[10];
    const float* tnz  = (const float*)d_in[11];
    const float* snz  = (const float*)d_in[12];
    const int* row   = (const int*)d_in[13];
    const int* colv  = (const int*)d_in[14];
    const int* rwcol = (const int*)d_in[16];

    const int n = NNODES;
    const int nE = in_sizes[1];

    float* out   = (float*)d_out;
    float* emb_t = out;
    float* emb_s = out + 3200000;
    float* masko = out + 6400002;

    // L1: misc prep
    misc_kernel<<<1771, 256, 0, stream>>>(x, tW1, sW1, row, n, nE);
    // L2a: P = X @ W1_halves
    prep2_kernel<<<782, 256, 0, stream>>>(n);
    // L2b: edge masks
    edge_mask_kernel<<<nE / 32, 256, 0, stream>>>(tb1, tW2, tb2, tnz,
                                                  row, colv, masko, nE);
    // L3: s1
    s1_kernel<<<6250, 256, 0, stream>>>(colv, vals, n);
    // L4: s2 + nm0
    s2_nm0_kernel<<<6250 + 782, 256, 0, stream>>>(colv, vals, x, emb_t,
                                                  sb1, sW2, sb2, snz, n);
    // L5: rwgate(x->g0) + nm1
    rw0_nm1_kernel<<<6250 + 782, 256, 0, stream>>>(rwcol, rwv,
                                                   sb1 + 64, sW2 + 64, sb2 + 1,
                                                   snz + n, n);
    // L6: c1 = spmm(vals, g0)
    spmm10_kernel<<<6250, 256, 0, stream>>>(colv, vals, n);
    // L7: g1 = rwgate(c1)
    rw1_kernel<<<6250, 256, 0, stream>>>(rwcol, rwv);
    // L8: emb_s + scalars
    spmm12_fin_kernel<<<6251, 256, 0, stream>>>(colv, vals, x, emb_s, out, n);
}

// Round 10
// 343.729 us; speedup vs baseline: 2.0564x; 1.0266x over previous
//
#include <hip/hip_runtime.h>

#define NNODES 50000
#define EDIM 64
#define WKLEN 9
#define NEDGE 800000
#define NPAD (NNODES + 64)

using bf16x8 = __attribute__((ext_vector_type(8))) __bf16;
using f32x4  = __attribute__((ext_vector_type(4))) float;

// ---- static device scratch ----
__device__ __align__(256) unsigned short g_xbf[NPAD * EDIM];     // bf16 x (padded)
__device__ __align__(256) unsigned short g_ABh[NNODES * 128];    // packed (cur1,t1)
__device__ __align__(256) unsigned short g_c1h[NPAD * EDIM];     // cur1 bf16 (nm0)
__device__ __align__(256) unsigned short g_c2h[NPAD * EDIM];     // cur2 bf16 (nm1)
__device__ __align__(256) unsigned short g_g0h[NNODES * EDIM];   // g0 then g1
__device__ __align__(256) unsigned short g_sc1h[NNODES * EDIM];  // s-branch c1
__device__ __align__(256) unsigned short g_Pr[NNODES * 128];     // x@W1top L0|L1
__device__ __align__(256) unsigned short g_Pc[NNODES * 128];     // x@W1bot L0|L1
__device__ __align__(256) float g_mt0[NEDGE];
__device__ __align__(256) float g_mt1[NEDGE];
__device__ __align__(256) float g_sm0[NNODES];
__device__ __align__(256) float g_sm1[NNODES];
__device__ __align__(256) int   g_rowptr[NNODES + 1];
__device__ __align__(256) unsigned short g_Tswz[2048 * 8];  // edge W1-half frags
__device__ __align__(256) unsigned short g_Sswz[1024 * 8];  // node-MLP W1 frags

__device__ __forceinline__ unsigned short f2bf(float f) {
    union { float f; unsigned int i; } v;
    v.f = f;
    unsigned int r = v.i + 0x7FFFu + ((v.i >> 16) & 1u);
    return (unsigned short)(r >> 16);
}
__device__ __forceinline__ float bf2f_lo(unsigned int u) {
    union { unsigned int i; float f; } v; v.i = u << 16; return v.f;
}
__device__ __forceinline__ float bf2f_hi(unsigned int u) {
    union { unsigned int i; float f; } v; v.i = u & 0xFFFF0000u; return v.f;
}

// ---------------------------------------------------------------------------
// L1: misc — x->bf16 | rowptr | W1-half swizzle (edge) | W1 swizzle (node)
// ---------------------------------------------------------------------------
__global__ __launch_bounds__(256) void misc_kernel(
    const float* __restrict__ x, const float* __restrict__ tW1,
    const float* __restrict__ sW1, const int* __restrict__ row,
    int n, int nE)
{
    int bid = blockIdx.x, tid = threadIdx.x;
    if (bid < 1563) {
        int i = bid * 256 + tid;
        if (i < NNODES * EDIM / 8) {
            const float* src = x + i * 8;
            union { unsigned short s[8]; uint4 q; } u;
#pragma unroll
            for (int j = 0; j < 8; ++j) u.s[j] = f2bf(src[j]);
            *(uint4*)&g_xbf[i * 8] = u.q;
        }
    } else if (bid < 1759) {
        int i = (bid - 1563) * 256 + tid;
        if (i > n) return;
        int lo = 0, hi = nE;
        while (lo < hi) {
            int mid = (lo + hi) >> 1;
            if (row[mid] < i) lo = mid + 1; else hi = mid;
        }
        g_rowptr[i] = lo;
    } else if (bid < 1767) {
        int t = (bid - 1759) * 256 + tid;   // 0..2047
        int s = t >> 9, f = (t >> 6) & 7, ln = t & 63;
        int li = s >> 1, half = s & 1, ks = f >> 2, nn = f & 3;
        int q = ln >> 4, mcl = ln & 15;
        union { unsigned short sv[8]; uint4 q4; } u;
#pragma unroll
        for (int j = 0; j < 8; ++j) {
            int kg = half * 64 + ks * 32 + q * 8 + j;
            u.sv[j] = f2bf(tW1[li * 8192 + kg * 64 + nn * 16 + mcl]);
        }
        *(uint4*)&g_Tswz[t * 8] = u.q4;
    } else {
        int t = (bid - 1767) * 256 + tid;  // 0..1023
        int li = t >> 9, ks = (t >> 8) & 1, nn = (t >> 6) & 3, ln = t & 63;
        int q = ln >> 4, mcl = ln & 15;
        union { unsigned short sv[8]; uint4 q4; } u;
#pragma unroll
        for (int j = 0; j < 8; ++j)
            u.sv[j] = f2bf(sW1[li * 4096 + (ks * 32 + q * 8 + j) * 64 + nn * 16 + mcl]);
        *(uint4*)&g_Sswz[t * 8] = u.q4;
    }
}

// ---------------------------------------------------------------------------
// L2a: prep2 — P = X @ W1_half for 4 sets via MFMA, bf16 packed out.
// ---------------------------------------------------------------------------
__global__ __launch_bounds__(256) void prep2_kernel(int n)
{
    int tid = threadIdx.x;
    int wave = tid >> 6, lane = tid & 63;
    int mc = lane & 15, quad = lane >> 4;
    int nb = blockIdx.x * 64 + wave * 16;
    const unsigned short* bp = g_xbf + (nb + mc) * 64 + quad * 8;
    bf16x8 af0 = *(const bf16x8*)bp;
    bf16x8 af1 = *(const bf16x8*)(bp + 32);
    const f32x4 zero = {0.f, 0.f, 0.f, 0.f};
#pragma unroll
    for (int s = 0; s < 4; ++s) {
        int li = s >> 1, half = s & 1;
        f32x4 acc[4];
#pragma unroll
        for (int nn = 0; nn < 4; ++nn) acc[nn] = zero;
#pragma unroll
        for (int nn = 0; nn < 4; ++nn) {
            bf16x8 b0 = *(const bf16x8*)&g_Tswz[((s * 8 + nn) * 64 + lane) * 8];
            bf16x8 b1 = *(const bf16x8*)&g_Tswz[((s * 8 + 4 + nn) * 64 + lane) * 8];
            acc[nn] = __builtin_amdgcn_mfma_f32_16x16x32_bf16(af0, b0, acc[nn], 0, 0, 0);
            acc[nn] = __builtin_amdgcn_mfma_f32_16x16x32_bf16(af1, b1, acc[nn], 0, 0, 0);
        }
        unsigned short* dst = half ? g_Pc : g_Pr;
#pragma unroll
        for (int nn = 0; nn < 4; ++nn)
#pragma unroll
            for (int r = 0; r < 4; ++r) {
                int node = nb + quad * 4 + r;
                if (node < n)
                    dst[node * 128 + li * 64 + nn * 16 + mc] = f2bf(acc[nn][r]);
            }
    }
}

// ---------------------------------------------------------------------------
// L2b: edge masks — wave = 8 edges x 8 lanes x 8 dims; no MFMA, no LDS.
// ---------------------------------------------------------------------------
__global__ __launch_bounds__(256) void edge_mask_kernel(
    const float* __restrict__ tb1, const float* __restrict__ tW2,
    const float* __restrict__ tb2, const float* __restrict__ tnoise,
    const int* __restrict__ row, const int* __restrict__ col,
    float* __restrict__ mask_out, int nE)
{
    int tid = threadIdx.x;
    int lane = tid & 63;
    int sub = lane & 7;
    int eg = lane >> 3;
    int wv = (blockIdx.x * 256 + tid) >> 6;
    int e = wv * 8 + eg;

    float b1_0[8], b1_1[8], w2_0[8], w2_1[8];
    *(float4*)&b1_0[0] = *(const float4*)&tb1[sub * 8];
    *(float4*)&b1_0[4] = *(const float4*)&tb1[sub * 8 + 4];
    *(float4*)&b1_1[0] = *(const float4*)&tb1[64 + sub * 8];
    *(float4*)&b1_1[4] = *(const float4*)&tb1[64 + sub * 8 + 4];
    *(float4*)&w2_0[0] = *(const float4*)&tW2[sub * 8];
    *(float4*)&w2_0[4] = *(const float4*)&tW2[sub * 8 + 4];
    *(float4*)&w2_1[0] = *(const float4*)&tW2[64 + sub * 8];
    *(float4*)&w2_1[4] = *(const float4*)&tW2[64 + sub * 8 + 4];

    int rn = row[e], cn = col[e];
    uint4 qr0 = *(const uint4*)&g_Pr[rn * 128 + sub * 8];
    uint4 qr1 = *(const uint4*)&g_Pr[rn * 128 + 64 + sub * 8];
    uint4 qc0 = *(const uint4*)&g_Pc[cn * 128 + sub * 8];
    uint4 qc1 = *(const uint4*)&g_Pc[cn * 128 + 64 + sub * 8];

    float p0 = 0.f, p1 = 0.f;
    unsigned r0[4] = {qr0.x, qr0.y, qr0.z, qr0.w};
    unsigned r1[4] = {qr1.x, qr1.y, qr1.z, qr1.w};
    unsigned c0[4] = {qc0.x, qc0.y, qc0.z, qc0.w};
    unsigned c1[4] = {qc1.x, qc1.y, qc1.z, qc1.w};
#pragma unroll
    for (int k = 0; k < 4; ++k) {
        float hA = fmaxf(bf2f_lo(r0[k]) + bf2f_lo(c0[k]) + b1_0[2 * k], 0.f);
        float hB = fmaxf(bf2f_hi(r0[k]) + bf2f_hi(c0[k]) + b1_0[2 * k + 1], 0.f);
        p0 = fmaf(hA, w2_0[2 * k], p0);
        p0 = fmaf(hB, w2_0[2 * k + 1], p0);
        float gA = fmaxf(bf2f_lo(r1[k]) + bf2f_lo(c1[k]) + b1_1[2 * k], 0.f);
        float gB = fmaxf(bf2f_hi(r1[k]) + bf2f_hi(c1[k]) + b1_1[2 * k + 1], 0.f);
        p1 = fmaf(gA, w2_1[2 * k], p1);
        p1 = fmaf(gB, w2_1[2 * k + 1], p1);
    }
#pragma unroll
    for (int off = 1; off <= 4; off <<= 1) {
        p0 += __shfl_xor(p0, off, 64);
        p1 += __shfl_xor(p1, off, 64);
    }
    if (sub == 0) {
        float z0 = (tnoise[e] + p0 + tb2[0]) * 2.0f;
        float m0 = 1.0f / (1.0f + expf(-z0));
        g_mt0[e] = m0;
        float z1 = (tnoise[nE + e] + p1 + tb2[1]) * 2.0f;
        float m1 = 1.0f / (1.0f + expf(-z1));
        g_mt1[e] = m1;
        mask_out[e] = m1;
    }
}

// ---------------------------------------------------------------------------
// node-MLP via MFMA: 16 nodes/wave
// ---------------------------------------------------------------------------
__device__ __forceinline__ void nm_body(
    int bid, const unsigned short* __restrict__ cur, int li,
    const float* __restrict__ b1, const float* __restrict__ W2,
    const float* __restrict__ b2, const float* __restrict__ noise,
    float* __restrict__ smout, int n)
{
    int tid = threadIdx.x;
    int wave = tid >> 6, lane = tid & 63;
    int mc = lane & 15, quad = lane >> 4;
    int nb = bid * 64 + wave * 16;
    const unsigned short* basep = cur + (nb + mc) * 64 + quad * 8;
    bf16x8 af0 = *(const bf16x8*)basep;
    bf16x8 af1 = *(const bf16x8*)(basep + 32);
    f32x4 acc[4];
    const f32x4 zero = {0.f, 0.f, 0.f, 0.f};
#pragma unroll
    for (int nn = 0; nn < 4; ++nn) acc[nn] = zero;
#pragma unroll
    for (int nn = 0; nn < 4; ++nn) {
        bf16x8 b0 = *(const bf16x8*)&g_Sswz[((li * 8 + nn) * 64 + lane) * 8];
        bf16x8 b1f = *(const bf16x8*)&g_Sswz[((li * 8 + 4 + nn) * 64 + lane) * 8];
        acc[nn] = __builtin_amdgcn_mfma_f32_16x16x32_bf16(af0, b0, acc[nn], 0, 0, 0);
        acc[nn] = __builtin_amdgcn_mfma_f32_16x16x32_bf16(af1, b1f, acc[nn], 0, 0, 0);
    }
    float p[4];
#pragma unroll
    for (int r = 0; r < 4; ++r) {
        float s = 0.f;
#pragma unroll
        for (int nn = 0; nn < 4; ++nn) {
            float h = acc[nn][r] + b1[nn * 16 + mc];
            s = fmaf(fmaxf(h, 0.f), W2[nn * 16 + mc], s);
        }
        p[r] = s;
    }
#pragma unroll
    for (int off = 8; off >= 1; off >>= 1)
#pragma unroll
        for (int r = 0; r < 4; ++r) p[r] += __shfl_xor(p[r], off, 64);
    if (mc == 0) {
        float b2v = b2[0];
#pragma unroll
        for (int r = 0; r < 4; ++r) {
            int node = nb + quad * 4 + r;
            if (node < n) {
                float z = (noise[node] + p[r] + b2v) * 2.0f;
                smout[node] = 1.0f / (1.0f + expf(-z));
            }
        }
    }
}

__global__ __launch_bounds__(256) void nm0_kernel(
    const float* __restrict__ sb1, const float* __restrict__ sW2,
    const float* __restrict__ sb2, const float* __restrict__ snz, int n)
{
    nm_body(blockIdx.x, g_c1h, 0, sb1, sW2, sb2, snz, g_sm0, n);
}

// ---------------------------------------------------------------------------
// L3: s1 — meta vector-load + shfl broadcast + 16 batched gathers.
// ---------------------------------------------------------------------------
__device__ __forceinline__ void s1_process16(
    int sb, int d2, int myc, float myv, float myvm,
    float& p0, float& p1, float& q0, float& q1)
{
    int cc[16]; float vv[16], mm[16]; unsigned uu[16];
#pragma unroll
    for (int k = 0; k < 16; ++k) {
        cc[k] = __shfl(myc, sb + k, 64);
        vv[k] = __shfl(myv, sb + k, 64);
        mm[k] = __shfl(myvm, sb + k, 64);
    }
#pragma unroll
    for (int k = 0; k < 16; ++k)
        uu[k] = *(const unsigned*)&g_xbf[cc[k] * 64 + 2 * d2];
#pragma unroll
    for (int k = 0; k < 16; ++k) {
        p0 = fmaf(vv[k], bf2f_lo(uu[k]), p0);
        p1 = fmaf(vv[k], bf2f_hi(uu[k]), p1);
        q0 = fmaf(mm[k], bf2f_lo(uu[k]), q0);
        q1 = fmaf(mm[k], bf2f_hi(uu[k]), q1);
    }
}

__global__ __launch_bounds__(256) void s1_kernel(
    const int* __restrict__ colv, const float* __restrict__ vals, int n)
{
    int half = threadIdx.x >> 5;
    int w = blockIdx.x * 8 + half;
    int el = half & 1;
    int d2 = threadIdx.x & 31;
    int sb0 = el << 5;
    int s = g_rowptr[w], e = g_rowptr[w + 1];
    float p0 = 0.f, p1 = 0.f, q0 = 0.f, q1 = 0.f;
    for (int base = s; base < e; base += 32) {
        int rem = e - base;
        int myc = 0; float myv = 0.f, myvm = 0.f;
        if (d2 < rem) {
            myc = colv[base + d2];
            myv = vals[base + d2];
            myvm = myv * g_mt0[base + d2];
        }
        s1_process16(sb0, d2, myc, myv, myvm, p0, p1, q0, q1);
        if (rem > 16)
            s1_process16(sb0 + 16, d2, myc, myv, myvm, p0, p1, q0, q1);
    }
    uint2 pk;
    pk.x = (unsigned)f2bf(p0) | ((unsigned)f2bf(q0) << 16);
    pk.y = (unsigned)f2bf(p1) | ((unsigned)f2bf(q1) << 16);
    *(uint2*)&g_ABh[w * 128 + 4 * d2] = pk;
    *(unsigned*)&g_c1h[w * 64 + 2 * d2] =
        (unsigned)f2bf(p0) | ((unsigned)f2bf(p1) << 16);
}

// ---------------------------------------------------------------------------
// s2 gather block: 8 edges, uint2 gathers
// ---------------------------------------------------------------------------
__device__ __forceinline__ void s2_process8(
    int sb, int d2, int myc, float myv, float myvm,
    float& c0, float& c1, float& t0, float& t1)
{
    int cc[8]; float vv[8], mm[8]; uint2 uu[8];
#pragma unroll
    for (int k = 0; k < 8; ++k) {
        cc[k] = __shfl(myc, sb + k, 64);
        vv[k] = __shfl(myv, sb + k, 64);
        mm[k] = __shfl(myvm, sb + k, 64);
    }
#pragma unroll
    for (int k = 0; k < 8; ++k)
        uu[k] = *(const uint2*)&g_ABh[cc[k] * 128 + 4 * d2];
#pragma unroll
    for (int k = 0; k < 8; ++k) {
        c0 = fmaf(vv[k], bf2f_lo(uu[k].x), c0);
        t0 = fmaf(mm[k], bf2f_hi(uu[k].x), t0);
        c1 = fmaf(vv[k], bf2f_lo(uu[k].y), c1);
        t1 = fmaf(mm[k], bf2f_hi(uu[k].y), t1);
    }
}

// ---------------------------------------------------------------------------
// L6: s2 (emb_t, c2h) || rw0 (g0)
// ---------------------------------------------------------------------------
__device__ __forceinline__ void rw_body(
    int bid, const int* __restrict__ rw_col, const float* __restrict__ rwv,
    const unsigned short* __restrict__ cur, const float* __restrict__ smask,
    unsigned short* __restrict__ outg)
{
    int w = bid * 8 + (threadIdx.x >> 5);
    int d2 = threadIdx.x & 31;
    int base = w * WKLEN;
    float a0 = 0.f, a1 = 0.f;
#pragma unroll
    for (int j = 0; j < WKLEN; ++j) {
        int c = rw_col[base + j];
        float v = rwv[base + j];
        unsigned u = *(const unsigned*)&cur[c * 64 + 2 * d2];
        a0 = fmaf(v, bf2f_lo(u), a0);
        a1 = fmaf(v, bf2f_hi(u), a1);
    }
    float sm = smask[w];
    unsigned u = *(const unsigned*)&cur[w * 64 + 2 * d2];
    float r0 = sm * bf2f_lo(u) + (1.f - sm) * a0;
    float r1 = sm * bf2f_hi(u) + (1.f - sm) * a1;
    *(unsigned*)&outg[w * 64 + 2 * d2] =
        (unsigned)f2bf(r0) | ((unsigned)f2bf(r1) << 16);
}

__global__ __launch_bounds__(256) void s2_rw0_kernel(
    const int* __restrict__ colv, const float* __restrict__ vals,
    const int* __restrict__ rw_col, const float* __restrict__ rwv,
    const float* __restrict__ x, float* __restrict__ emb_t, int n)
{
    if (blockIdx.x >= 6250) {
        rw_body(blockIdx.x - 6250, rw_col, rwv, g_xbf, g_sm0, g_g0h);
        return;
    }
    int half = threadIdx.x >> 5;
    int w = blockIdx.x * 8 + half;
    int el = half & 1;
    int d2 = threadIdx.x & 31;
    int sb0 = el << 5;
    int s = g_rowptr[w], e = g_rowptr[w + 1];
    float c0 = 0.f, c1 = 0.f, t0 = 0.f, t1 = 0.f;
    for (int base = s; base < e; base += 32) {
        int rem = e - base;
        int myc = 0; float myv = 0.f, myvm = 0.f;
        if (d2 < rem) {
            myc = colv[base + d2];
            myv = vals[base + d2];
            myvm = myv * g_mt1[base + d2];
        }
        s2_process8(sb0, d2, myc, myv, myvm, c0, c1, t0, t1);
        if (rem > 8)  s2_process8(sb0 + 8,  d2, myc, myv, myvm, c0, c1, t0, t1);
        if (rem > 16) s2_process8(sb0 + 16, d2, myc, myv, myvm, c0, c1, t0, t1);
        if (rem > 24) s2_process8(sb0 + 24, d2, myc, myv, myvm, c0, c1, t0, t1);
    }
    int o2 = w * 64 + 2 * d2;
    uint2 U2v = *(const uint2*)&g_ABh[w * 128 + 4 * d2];
    float2 et;
    et.x = (x[o2]     + bf2f_hi(U2v.x) + t0) * (1.0f / 3.0f);
    et.y = (x[o2 + 1] + bf2f_hi(U2v.y) + t1) * (1.0f / 3.0f);
    *(float2*)&emb_t[o2] = et;
    *(unsigned*)&g_c2h[o2] = (unsigned)f2bf(c0) | ((unsigned)f2bf(c1) << 16);
}

// ---------------------------------------------------------------------------
// generic spmm body: 16 batched gathers from bf16 h
// ---------------------------------------------------------------------------
__device__ __forceinline__ void sp_process16(
    const unsigned short* __restrict__ h, int sb, int d2,
    int myc, float myv, float& a0, float& a1)
{
    int cc[16]; float vv[16]; unsigned uu[16];
#pragma unroll
    for (int k = 0; k < 16; ++k) {
        cc[k] = __shfl(myc, sb + k, 64);
        vv[k] = __shfl(myv, sb + k, 64);
    }
#pragma unroll
    for (int k = 0; k < 16; ++k)
        uu[k] = *(const unsigned*)&h[cc[k] * 64 + 2 * d2];
#pragma unroll
    for (int k = 0; k < 16; ++k) {
        a0 = fmaf(vv[k], bf2f_lo(uu[k]), a0);
        a1 = fmaf(vv[k], bf2f_hi(uu[k]), a1);
    }
}

__device__ __forceinline__ void spmm_body(
    int bid, const int* __restrict__ colv, const float* __restrict__ vals,
    const unsigned short* __restrict__ h, float* __restrict__ l0,
    float* __restrict__ l1, int* __restrict__ wout, int* __restrict__ d2out)
{
    int half = threadIdx.x >> 5;
    int w = bid * 8 + half;
    int el = half & 1;
    int d2 = threadIdx.x & 31;
    int sb0 = el << 5;
    int s = g_rowptr[w], e = g_rowptr[w + 1];
    float a0 = 0.f, a1 = 0.f;
    for (int base = s; base < e; base += 32) {
        int rem = e - base;
        int myc = 0; float myv = 0.f;
        if (d2 < rem) {
            myc = colv[base + d2];
            myv = vals[base + d2];
        }
        sp_process16(h, sb0, d2, myc, myv, a0, a1);
        if (rem > 16) sp_process16(h, sb0 + 16, d2, myc, myv, a0, a1);
    }
    *l0 = a0; *l1 = a1; *wout = w; *d2out = d2;
}

// ---------------------------------------------------------------------------
// L7: spmm10 (sc1 = A·g0) || nm1 (sm1 from c2h)
// ---------------------------------------------------------------------------
__global__ __launch_bounds__(256) void spmm10_nm1_kernel(
    const int* __restrict__ colv, const float* __restrict__ vals,
    const float* __restrict__ sb1, const float* __restrict__ sW2,
    const float* __restrict__ sb2, const float* __restrict__ snz, int n)
{
    if (blockIdx.x >= 6250) {
        nm_body(blockIdx.x - 6250, g_c2h, 1, sb1, sW2, sb2, snz, g_sm1, n);
        return;
    }
    float a0, a1; int w, d2;
    spmm_body(blockIdx.x, colv, vals, g_g0h, &a0, &a1, &w, &d2);
    *(unsigned*)&g_sc1h[w * 64 + 2 * d2] =
        (unsigned)f2bf(a0) | ((unsigned)f2bf(a1) << 16);
}

// ---------------------------------------------------------------------------
// L8: g1 = rwgate(c1)
// ---------------------------------------------------------------------------
__global__ __launch_bounds__(256) void rw1_kernel(
    const int* __restrict__ rw_col, const float* __restrict__ rwv)
{
    rw_body(blockIdx.x, rw_col, rwv, g_sc1h, g_sm1, g_g0h);
}

// ---------------------------------------------------------------------------
// L9: emb_s = (x + c1 + spmm(vals, g1))/3, merged with finalize
// ---------------------------------------------------------------------------
__global__ __launch_bounds__(256) void spmm12_fin_kernel(
    const int* __restrict__ colv, const float* __restrict__ vals,
    const float* __restrict__ x, float* __restrict__ emb_s,
    float* __restrict__ out, int n)
{
    if (blockIdx.x >= 6250) {
        __shared__ float red[256];
        float s = 0.f;
        for (int i = threadIdx.x; i < n; i += 256) s += g_sm0[i] + g_sm1[i];
        red[threadIdx.x] = s;
        __syncthreads();
        for (int off = 128; off >= 1; off >>= 1) {
            if (threadIdx.x < off) red[threadIdx.x] += red[threadIdx.x + off];
            __syncthreads();
        }
        if (threadIdx.x == 0) {
            out[6400000] = 0.0f;
            out[6400001] = red[0] / (2.0f * n);
        }
        return;
    }
    float a0, a1; int w, d2;
    spmm_body(blockIdx.x, colv, vals, g_g0h, &a0, &a1, &w, &d2);
    int o2 = w * 64 + 2 * d2;
    unsigned uc = *(const unsigned*)&g_sc1h[o2];
    float2 es;
    es.x = (x[o2]     + bf2f_lo(uc) + a0) * (1.0f / 3.0f);
    es.y = (x[o2 + 1] + bf2f_hi(uc) + a1) * (1.0f / 3.0f);
    *(float2*)&emb_s[o2] = es;
}

extern "C" void kernel_launch(void* const* d_in, const int* in_sizes, int n_in,
                              void* d_out, int out_size, void* d_ws, size_t ws_size,
                              hipStream_t stream)
{
    const float* x    = (const float*)d_in[0];
    const float* vals = (const float*)d_in[1];
    const float* rwv  = (const float*)d_in[2];
    const float* tW1  = (const float*)d_in[3];
    const float* tb1  = (const float*)d_in[4];
    const float* tW2  = (const float*)d_in[5];
    const float* tb2  = (const float*)d_in[6];
    const float* sW1  = (const float*)d_in[7];
    const float* sb1  = (const float*)d_in[8];
    const float* sW2  = (const float*)d_in[9];
    const float* sb2  = (const float*)d_in[10];
    const float* tnz  = (const float*)d_in[11];
    const float* snz  = (const float*)d_in[12];
    const int* row   = (const int*)d_in[13];
    const int* colv  = (const int*)d_in[14];
    const int* rwcol = (const int*)d_in[16];

    const int n = NNODES;
    const int nE = in_sizes[1];

    float* out   = (float*)d_out;
    float* emb_t = out;
    float* emb_s = out + 3200000;
    float* masko = out + 6400002;

    // L1: misc prep
    misc_kernel<<<1771, 256, 0, stream>>>(x, tW1, sW1, row, n, nE);
    // L2a: P = X @ W1_halves
    prep2_kernel<<<782, 256, 0, stream>>>(n);
    // L2b: edge masks
    edge_mask_kernel<<<nE / 32, 256, 0, stream>>>(tb1, tW2, tb2, tnz,
                                                  row, colv, masko, nE);
    // L3: s1 (cur1|t1 packed + cur1h)
    s1_kernel<<<6250, 256, 0, stream>>>(colv, vals, n);
    // L4: nm0 -> sm0
    nm0_kernel<<<782, 256, 0, stream>>>(sb1, sW2, sb2, snz, n);
    // L5: s2 || rw0
    s2_rw0_kernel<<<12500, 256, 0, stream>>>(colv, vals, rwcol, rwv, x, emb_t, n);
    // L6: spmm10 || nm1
    spmm10_nm1_kernel<<<6250 + 782, 256, 0, stream>>>(colv, vals,
                                                      sb1 + 64, sW2 + 64, sb2 + 1,
                                                      snz + n, n);
    // L7: g1 = rwgate(c1)
    rw1_kernel<<<6250, 256, 0, stream>>>(rwcol, rwv);
    // L8: emb_s + scalars
    spmm12_fin_kernel<<<6251, 256, 0, stream>>>(colv, vals, x, emb_s, out, n);
}